// Round 2
// baseline (1059.491 us; speedup 1.0000x reference)
//
#include <hip/hip_runtime.h>

#define N_NODES 100000
#define IN_CH 2048
#define OUT_CH 128
#define NNZ_FEAT 2000000
#define NNZ_ADJ 1600000
#define NTOT (2 * N_NODES)          // 200000 combined row counters
#define NSC (NTOT + 1)              // 200001 scan length (padded)
#define NNZ_TOT (NNZ_FEAT + NNZ_ADJ)

// ---------------- combined CSR build ----------------

__global__ void k_zero(int* __restrict__ C) {
    int i = blockIdx.x * blockDim.x + threadIdx.x;
    if (i < NSC) C[i] = 0;
}

__global__ void k_count(const int* __restrict__ frows, const int* __restrict__ arows,
                        int* __restrict__ C) {
    int i = blockIdx.x * blockDim.x + threadIdx.x;
    if (i < NNZ_FEAT) {
        atomicAdd(&C[frows[i]], 1);
    } else if (i < NNZ_TOT) {
        atomicAdd(&C[N_NODES + arows[i - NNZ_FEAT]], 1);
    }
}

// exclusive scan stage 1: per-block scan of 1024 elements
__global__ void k_scan1(const int* __restrict__ in, int* __restrict__ out,
                        int* __restrict__ bsums) {
    __shared__ int s[1024];
    int tid = threadIdx.x;
    int i = blockIdx.x * 1024 + tid;
    int v = (i < NSC) ? in[i] : 0;
    s[tid] = v;
    __syncthreads();
    for (int off = 1; off < 1024; off <<= 1) {
        int t = (tid >= off) ? s[tid - off] : 0;
        __syncthreads();
        s[tid] += t;
        __syncthreads();
    }
    if (i < NSC) out[i] = s[tid] - v;  // exclusive
    if (tid == 1023) bsums[blockIdx.x] = s[1023];
}

// stage 2: exclusive scan of block sums (nb <= 256) in one block of 256
__global__ void k_scan2(int* __restrict__ bsums, int nb) {
    __shared__ int s[256];
    int tid = threadIdx.x;
    int v = (tid < nb) ? bsums[tid] : 0;
    s[tid] = v;
    __syncthreads();
    for (int off = 1; off < 256; off <<= 1) {
        int t = (tid >= off) ? s[tid - off] : 0;
        __syncthreads();
        s[tid] += t;
        __syncthreads();
    }
    if (tid < nb) bsums[tid] = s[tid] - v;
}

// stage 3: add scanned block offsets; also emit the mutable cursor copy
__global__ void k_scan3(int* __restrict__ S, const int* __restrict__ bsums,
                        int* __restrict__ cur) {
    int i = blockIdx.x * 1024 + threadIdx.x;
    if (i < NSC) {
        int v = S[i] + bsums[blockIdx.x];
        S[i] = v;
        if (i < NTOT) cur[i] = v;
    }
}

// scatter both COO lists into one combined CSR of int2{col, val_bits}
__global__ void k_scatter(const int* __restrict__ frows, const int* __restrict__ fcols,
                          const float* __restrict__ fvals,
                          const int* __restrict__ arows, const int* __restrict__ acols,
                          const float* __restrict__ avals,
                          int* __restrict__ cur, int2* __restrict__ pairs) {
    int i = blockIdx.x * blockDim.x + threadIdx.x;
    if (i >= NNZ_TOT) return;
    int r, c;
    float v;
    if (i < NNZ_FEAT) {
        r = frows[i];
        c = fcols[i];
        v = fvals[i];
    } else {
        int j = i - NNZ_FEAT;
        r = N_NODES + arows[j];
        c = acols[j];
        v = avals[j];
    }
    int p = atomicAdd(&cur[r], 1);
    pairs[p] = make_int2(c, __float_as_int(v));
}

// ---------------- SpMM kernels (one 64-lane wave per row, float2/lane) ----------------

__global__ __launch_bounds__(256) void spmm_w(const int* __restrict__ S,
                                              const int2* __restrict__ pairs,
                                              const float* __restrict__ W,
                                              const float* __restrict__ bias,
                                              float* __restrict__ out) {
    int row = blockIdx.x * 4 + (threadIdx.x >> 6);
    int lane = threadIdx.x & 63;
    int k0 = S[row], k1 = S[row + 1];
    float2 acc = ((const float2*)bias)[lane];
    for (int k = k0; k < k1; ++k) {
        int2 p = pairs[k];
        float v = __int_as_float(p.y);
        float2 w = ((const float2*)(W + (size_t)p.x * OUT_CH))[lane];
        acc.x = fmaf(v, w.x, acc.x);
        acc.y = fmaf(v, w.y, acc.y);
    }
    float2 r;
    r.x = fmaxf(acc.x, 0.0f);
    r.y = fmaxf(acc.y, 0.0f);
    ((float2*)(out + (size_t)row * OUT_CH))[lane] = r;
}

__global__ __launch_bounds__(256) void spmm_adj(const int* __restrict__ S,
                                                const int2* __restrict__ pairs,
                                                const float* __restrict__ hin,
                                                float* __restrict__ hout) {
    int row = blockIdx.x * 4 + (threadIdx.x >> 6);
    int lane = threadIdx.x & 63;
    int k0 = S[N_NODES + row], k1 = S[N_NODES + row + 1];
    float2 acc = make_float2(0.0f, 0.0f);
    for (int k = k0; k < k1; ++k) {
        int2 p = pairs[k];
        float v = __int_as_float(p.y);
        float2 h = ((const float2*)(hin + (size_t)p.x * OUT_CH))[lane];
        acc.x = fmaf(v, h.x, acc.x);
        acc.y = fmaf(v, h.y, acc.y);
    }
    ((float2*)(hout + (size_t)row * OUT_CH))[lane] = acc;
}

// ---------------- driver ----------------

extern "C" void kernel_launch(void* const* d_in, const int* in_sizes, int n_in,
                              void* d_out, int out_size, void* d_ws, size_t ws_size,
                              hipStream_t stream) {
    const int*   frows = (const int*)d_in[0];
    const int*   fcols = (const int*)d_in[1];
    const float* fvals = (const float*)d_in[2];
    const int*   arows = (const int*)d_in[3];
    const int*   acols = (const int*)d_in[4];
    const float* avals = (const float*)d_in[5];
    const float* W     = (const float*)d_in[6];
    const float* bias  = (const float*)d_in[7];
    float* out = (float*)d_out;

    char* ws = (char*)d_ws;
    size_t off = 0;
    auto alloc = [&](size_t bytes) {
        size_t o = off;
        off = (off + bytes + 255) & ~(size_t)255;
        return o;
    };
    int*  C    = (int*) (ws + alloc((size_t)NSC * 4));
    int*  S    = (int*) (ws + alloc((size_t)NSC * 4));
    int*  cur  = (int*) (ws + alloc((size_t)NTOT * 4));
    int*  bsum = (int*) (ws + alloc(256 * 4));
    int2* pairs = (int2*)(ws + alloc((size_t)NNZ_TOT * 8));
    float* hbuf = (float*)(ws + alloc((size_t)N_NODES * OUT_CH * 4));
    (void)ws_size; (void)off; (void)in_sizes; (void)n_in; (void)out_size;

    const int nscan = (NSC + 1023) / 1024;  // 196

    k_zero<<<(NSC + 255) / 256, 256, 0, stream>>>(C);
    k_count<<<(NNZ_TOT + 255) / 256, 256, 0, stream>>>(frows, arows, C);
    k_scan1<<<nscan, 1024, 0, stream>>>(C, S, bsum);
    k_scan2<<<1, 256, 0, stream>>>(bsum, nscan);
    k_scan3<<<nscan, 1024, 0, stream>>>(S, bsum, cur);
    k_scatter<<<(NNZ_TOT + 255) / 256, 256, 0, stream>>>(frows, fcols, fvals,
                                                         arows, acols, avals, cur, pairs);

    spmm_w<<<N_NODES / 4, 256, 0, stream>>>(S, pairs, W, bias, hbuf);

    spmm_adj<<<N_NODES / 4, 256, 0, stream>>>(S, pairs, hbuf, out);
    spmm_adj<<<N_NODES / 4, 256, 0, stream>>>(S, pairs, out, hbuf);
    spmm_adj<<<N_NODES / 4, 256, 0, stream>>>(S, pairs, hbuf, out);
}

// Round 3
// 765.282 us; speedup vs baseline: 1.3844x; 1.3844x over previous
//
#include <hip/hip_runtime.h>

#define N_NODES 100000
#define IN_CH 2048
#define OUT_CH 128
#define NNZ_FEAT 2000000
#define NNZ_ADJ 1600000
#define NNZ_TOT (NNZ_FEAT + NNZ_ADJ)
#define NCOMB (2 * N_NODES)            // combined row space: feat rows then adj rows
#define BROWS 512                      // rows per bucket
#define NBUCK 391                      // ceil(200000 / 512)
#define NROWP (NBUCK * BROWS)          // 200192 padded row-count length
#define KB_BLOCK 256
#define KB_ITEMS 32
#define KB_CHUNK (KB_BLOCK * KB_ITEMS) // 8192
#define KB_GRID ((NNZ_TOT + KB_CHUNK - 1) / KB_CHUNK)

// ---------------- stage A: bucket histogram (LDS-aggregated) ----------------

__global__ __launch_bounds__(KB_BLOCK) void kA(const int* __restrict__ frows,
                                               const int* __restrict__ arows,
                                               int* __restrict__ bcnt) {
    __shared__ int hist[NBUCK];
    for (int t = threadIdx.x; t < NBUCK; t += KB_BLOCK) hist[t] = 0;
    __syncthreads();
    long base = (long)blockIdx.x * KB_CHUNK;
    for (int j = 0; j < KB_ITEMS; ++j) {
        long i = base + j * KB_BLOCK + threadIdx.x;
        if (i < NNZ_TOT) {
            int r = (i < NNZ_FEAT) ? frows[i] : (N_NODES + arows[i - NNZ_FEAT]);
            atomicAdd(&hist[r >> 9], 1);
        }
    }
    __syncthreads();
    for (int t = threadIdx.x; t < NBUCK; t += KB_BLOCK)
        if (hist[t]) atomicAdd(&bcnt[t], hist[t]);
}

// scan 391 bucket counts in one block of 512; emit boff (exclusive) and gcur copy
__global__ void k_scanb(const int* __restrict__ bcnt, int* __restrict__ boff,
                        int* __restrict__ gcur) {
    __shared__ int s[512];
    int t = threadIdx.x;
    int v = (t < NBUCK) ? bcnt[t] : 0;
    s[t] = v;
    __syncthreads();
    for (int off = 1; off < 512; off <<= 1) {
        int x = (t >= off) ? s[t - off] : 0;
        __syncthreads();
        s[t] += x;
        __syncthreads();
    }
    int e = s[t] - v;
    if (t < NBUCK) { boff[t] = e; gcur[t] = e; }
    if (t == NBUCK - 1) boff[NBUCK] = s[t];
}

// ---------------- stage B: scatter into bucket regions ----------------

__global__ __launch_bounds__(KB_BLOCK) void kB(const int* __restrict__ frows,
                                               const int* __restrict__ fcols,
                                               const float* __restrict__ fvals,
                                               const int* __restrict__ arows,
                                               const int* __restrict__ acols,
                                               const float* __restrict__ avals,
                                               int* __restrict__ gcur,
                                               int* __restrict__ tmp_row,
                                               int2* __restrict__ tmp_cv) {
    __shared__ int hist[NBUCK];
    __shared__ int lcur[NBUCK];
    for (int t = threadIdx.x; t < NBUCK; t += KB_BLOCK) hist[t] = 0;
    __syncthreads();
    long base = (long)blockIdx.x * KB_CHUNK;
    int rr[KB_ITEMS];
    for (int j = 0; j < KB_ITEMS; ++j) {
        long i = base + j * KB_BLOCK + threadIdx.x;
        int r = -1;
        if (i < NNZ_TOT) {
            r = (i < NNZ_FEAT) ? frows[i] : (N_NODES + arows[i - NNZ_FEAT]);
            atomicAdd(&hist[r >> 9], 1);
        }
        rr[j] = r;
    }
    __syncthreads();
    for (int t = threadIdx.x; t < NBUCK; t += KB_BLOCK) {
        int h = hist[t];
        lcur[t] = h ? atomicAdd(&gcur[t], h) : 0;
    }
    __syncthreads();
    for (int j = 0; j < KB_ITEMS; ++j) {
        int r = rr[j];
        if (r >= 0) {
            long i = base + j * KB_BLOCK + threadIdx.x;
            int c; float v;
            if (i < NNZ_FEAT) { c = fcols[i]; v = fvals[i]; }
            else              { c = acols[i - NNZ_FEAT]; v = avals[i - NNZ_FEAT]; }
            int p = atomicAdd(&lcur[r >> 9], 1);
            tmp_row[p] = r;
            tmp_cv[p] = make_int2(c, __float_as_int(v));
        }
    }
}

// ---------------- stage C1: per-bucket row counts (LDS only) ----------------

__global__ __launch_bounds__(256) void kC1(const int* __restrict__ boff,
                                           const int* __restrict__ tmp_row,
                                           int* __restrict__ C) {
    __shared__ int rcnt[BROWS];
    int b = blockIdx.x, rbase = b << 9;
    rcnt[threadIdx.x] = 0;
    rcnt[threadIdx.x + 256] = 0;
    __syncthreads();
    int e0 = boff[b], e1 = boff[b + 1];
    for (int i = e0 + threadIdx.x; i < e1; i += 256)
        atomicAdd(&rcnt[tmp_row[i] - rbase], 1);
    __syncthreads();
    C[rbase + threadIdx.x] = rcnt[threadIdx.x];
    C[rbase + threadIdx.x + 256] = rcnt[threadIdx.x + 256];
}

// ---------------- row-offset scan over NROWP ----------------

__global__ void k_scan1(const int* __restrict__ in, int* __restrict__ out,
                        int* __restrict__ bsums) {
    __shared__ int s[1024];
    int tid = threadIdx.x;
    int i = blockIdx.x * 1024 + tid;
    int v = (i < NROWP) ? in[i] : 0;
    s[tid] = v;
    __syncthreads();
    for (int off = 1; off < 1024; off <<= 1) {
        int t = (tid >= off) ? s[tid - off] : 0;
        __syncthreads();
        s[tid] += t;
        __syncthreads();
    }
    if (i < NROWP) out[i] = s[tid] - v;  // exclusive
    if (tid == 1023) bsums[blockIdx.x] = s[1023];
}

__global__ void k_scan2(int* __restrict__ bsums, int nb) {
    __shared__ int s[256];
    int tid = threadIdx.x;
    int v = (tid < nb) ? bsums[tid] : 0;
    s[tid] = v;
    __syncthreads();
    for (int off = 1; off < 256; off <<= 1) {
        int t = (tid >= off) ? s[tid - off] : 0;
        __syncthreads();
        s[tid] += t;
        __syncthreads();
    }
    if (tid < nb) bsums[tid] = s[tid] - v;
}

__global__ void k_scan3(int* __restrict__ S, const int* __restrict__ bsums) {
    int i = blockIdx.x * 1024 + threadIdx.x;
    if (i < NROWP) S[i] += bsums[blockIdx.x];
}

// ---------------- stage C2: place within bucket (LDS row cursors) ----------------

__global__ __launch_bounds__(256) void kC2(const int* __restrict__ boff,
                                           const int* __restrict__ S,
                                           const int* __restrict__ tmp_row,
                                           const int2* __restrict__ tmp_cv,
                                           int2* __restrict__ pairs) {
    __shared__ int rcur[BROWS];
    int b = blockIdx.x, rbase = b << 9;
    rcur[threadIdx.x] = S[rbase + threadIdx.x];
    rcur[threadIdx.x + 256] = S[rbase + threadIdx.x + 256];
    __syncthreads();
    int e0 = boff[b], e1 = boff[b + 1];
    for (int i = e0 + threadIdx.x; i < e1; i += 256) {
        int r = tmp_row[i];
        int p = atomicAdd(&rcur[r - rbase], 1);
        pairs[p] = tmp_cv[i];
    }
}

// ---------------- SpMM kernels (one 64-lane wave per row, float2/lane) ----------------

__global__ __launch_bounds__(256) void spmm_w(const int* __restrict__ S,
                                              const int2* __restrict__ pairs,
                                              const float* __restrict__ W,
                                              const float* __restrict__ bias,
                                              float* __restrict__ out) {
    int row = blockIdx.x * 4 + (threadIdx.x >> 6);
    int lane = threadIdx.x & 63;
    int k0 = S[row], k1 = S[row + 1];
    float2 acc = ((const float2*)bias)[lane];
    for (int k = k0; k < k1; ++k) {
        int2 p = pairs[k];
        float v = __int_as_float(p.y);
        float2 w = ((const float2*)(W + (size_t)p.x * OUT_CH))[lane];
        acc.x = fmaf(v, w.x, acc.x);
        acc.y = fmaf(v, w.y, acc.y);
    }
    float2 r;
    r.x = fmaxf(acc.x, 0.0f);
    r.y = fmaxf(acc.y, 0.0f);
    ((float2*)(out + (size_t)row * OUT_CH))[lane] = r;
}

__global__ __launch_bounds__(256) void spmm_adj(const int* __restrict__ S,
                                                const int2* __restrict__ pairs,
                                                const float* __restrict__ hin,
                                                float* __restrict__ hout) {
    int row = blockIdx.x * 4 + (threadIdx.x >> 6);
    int lane = threadIdx.x & 63;
    int k0 = S[N_NODES + row], k1 = S[N_NODES + row + 1];
    float2 acc = make_float2(0.0f, 0.0f);
    for (int k = k0; k < k1; ++k) {
        int2 p = pairs[k];
        float v = __int_as_float(p.y);
        float2 h = ((const float2*)(hin + (size_t)p.x * OUT_CH))[lane];
        acc.x = fmaf(v, h.x, acc.x);
        acc.y = fmaf(v, h.y, acc.y);
    }
    ((float2*)(hout + (size_t)row * OUT_CH))[lane] = acc;
}

// ---------------- driver ----------------

extern "C" void kernel_launch(void* const* d_in, const int* in_sizes, int n_in,
                              void* d_out, int out_size, void* d_ws, size_t ws_size,
                              hipStream_t stream) {
    const int*   frows = (const int*)d_in[0];
    const int*   fcols = (const int*)d_in[1];
    const float* fvals = (const float*)d_in[2];
    const int*   arows = (const int*)d_in[3];
    const int*   acols = (const int*)d_in[4];
    const float* avals = (const float*)d_in[5];
    const float* W     = (const float*)d_in[6];
    const float* bias  = (const float*)d_in[7];
    float* out = (float*)d_out;

    char* ws = (char*)d_ws;
    size_t off = 0;
    auto alloc = [&](size_t bytes) {
        size_t o = off;
        off = (off + bytes + 255) & ~(size_t)255;
        return o;
    };
    int*  C     = (int*) (ws + alloc((size_t)NROWP * 4));
    int*  S     = (int*) (ws + alloc((size_t)NROWP * 4));
    int*  bcnt  = (int*) (ws + alloc(400 * 4));
    int*  boff  = (int*) (ws + alloc(400 * 4));
    int*  gcur  = (int*) (ws + alloc(400 * 4));
    int*  bsum  = (int*) (ws + alloc(256 * 4));
    int2* pairs = (int2*)(ws + alloc((size_t)NNZ_TOT * 8));
    char* hraw  = ws + alloc((size_t)N_NODES * OUT_CH * 4);
    float* hbuf = (float*)hraw;
    // tmp buffers alias onto hbuf: dead before spmm_w runs
    int*  tmp_row = (int*)hraw;                                        // 14.4 MB
    int2* tmp_cv  = (int2*)(hraw + (((size_t)NNZ_TOT * 4 + 255) & ~(size_t)255)); // 28.8 MB
    (void)ws_size; (void)off; (void)in_sizes; (void)n_in; (void)out_size;

    const int nscan = (NROWP + 1023) / 1024;  // 196

    hipMemsetAsync(bcnt, 0, 400 * 4, stream);
    kA<<<KB_GRID, KB_BLOCK, 0, stream>>>(frows, arows, bcnt);
    k_scanb<<<1, 512, 0, stream>>>(bcnt, boff, gcur);
    kB<<<KB_GRID, KB_BLOCK, 0, stream>>>(frows, fcols, fvals, arows, acols, avals,
                                         gcur, tmp_row, tmp_cv);
    kC1<<<NBUCK, 256, 0, stream>>>(boff, tmp_row, C);
    k_scan1<<<nscan, 1024, 0, stream>>>(C, S, bsum);
    k_scan2<<<1, 256, 0, stream>>>(bsum, nscan);
    k_scan3<<<nscan, 1024, 0, stream>>>(S, bsum);
    kC2<<<NBUCK, 256, 0, stream>>>(boff, S, tmp_row, tmp_cv, pairs);

    spmm_w<<<N_NODES / 4, 256, 0, stream>>>(S, pairs, W, bias, hbuf);

    spmm_adj<<<N_NODES / 4, 256, 0, stream>>>(S, pairs, hbuf, out);
    spmm_adj<<<N_NODES / 4, 256, 0, stream>>>(S, pairs, out, hbuf);
    spmm_adj<<<N_NODES / 4, 256, 0, stream>>>(S, pairs, hbuf, out);
}

// Round 4
// 542.666 us; speedup vs baseline: 1.9524x; 1.4102x over previous
//
#include <hip/hip_runtime.h>

#define N_NODES 100000
#define IN_CH 2048
#define OUT_CH 128
#define NNZ_FEAT 2000000
#define NNZ_ADJ 1600000
#define NNZ_TOT (NNZ_FEAT + NNZ_ADJ)
#define NCOMB (2 * N_NODES)            // combined row space: feat rows then adj rows
#define BROWS 512                      // rows per bucket
#define NBUCK 391                      // ceil(200000 / 512)
#define NROWP (NBUCK * BROWS)          // 200192 padded row-count length
#define KB_BLOCK 256
#define KB_ITEMS 32
#define KB_CHUNK (KB_BLOCK * KB_ITEMS) // 8192
#define KB_GRID ((NNZ_TOT + KB_CHUNK - 1) / KB_CHUNK)

// ---------------- stage A: bucket histogram (LDS-aggregated) ----------------

__global__ __launch_bounds__(KB_BLOCK) void kA(const int* __restrict__ frows,
                                               const int* __restrict__ arows,
                                               int* __restrict__ bcnt) {
    __shared__ int hist[NBUCK];
    for (int t = threadIdx.x; t < NBUCK; t += KB_BLOCK) hist[t] = 0;
    __syncthreads();
    long base = (long)blockIdx.x * KB_CHUNK;
    for (int j = 0; j < KB_ITEMS; ++j) {
        long i = base + j * KB_BLOCK + threadIdx.x;
        if (i < NNZ_TOT) {
            int r = (i < NNZ_FEAT) ? frows[i] : (N_NODES + arows[i - NNZ_FEAT]);
            atomicAdd(&hist[r >> 9], 1);
        }
    }
    __syncthreads();
    for (int t = threadIdx.x; t < NBUCK; t += KB_BLOCK)
        if (hist[t]) atomicAdd(&bcnt[t], hist[t]);
}

// scan 391 bucket counts in one block of 512; emit boff (exclusive) and gcur copy
__global__ void k_scanb(const int* __restrict__ bcnt, int* __restrict__ boff,
                        int* __restrict__ gcur) {
    __shared__ int s[512];
    int t = threadIdx.x;
    int v = (t < NBUCK) ? bcnt[t] : 0;
    s[t] = v;
    __syncthreads();
    for (int off = 1; off < 512; off <<= 1) {
        int x = (t >= off) ? s[t - off] : 0;
        __syncthreads();
        s[t] += x;
        __syncthreads();
    }
    int e = s[t] - v;
    if (t < NBUCK) { boff[t] = e; gcur[t] = e; }
    if (t == NBUCK - 1) boff[NBUCK] = s[t];
}

// ---------------- stage B: scatter into bucket regions ----------------

__global__ __launch_bounds__(KB_BLOCK) void kB(const int* __restrict__ frows,
                                               const int* __restrict__ fcols,
                                               const float* __restrict__ fvals,
                                               const int* __restrict__ arows,
                                               const int* __restrict__ acols,
                                               const float* __restrict__ avals,
                                               int* __restrict__ gcur,
                                               int* __restrict__ tmp_row,
                                               int2* __restrict__ tmp_cv) {
    __shared__ int hist[NBUCK];
    __shared__ int lcur[NBUCK];
    for (int t = threadIdx.x; t < NBUCK; t += KB_BLOCK) hist[t] = 0;
    __syncthreads();
    long base = (long)blockIdx.x * KB_CHUNK;
    int rr[KB_ITEMS];
    for (int j = 0; j < KB_ITEMS; ++j) {
        long i = base + j * KB_BLOCK + threadIdx.x;
        int r = -1;
        if (i < NNZ_TOT) {
            r = (i < NNZ_FEAT) ? frows[i] : (N_NODES + arows[i - NNZ_FEAT]);
            atomicAdd(&hist[r >> 9], 1);
        }
        rr[j] = r;
    }
    __syncthreads();
    for (int t = threadIdx.x; t < NBUCK; t += KB_BLOCK) {
        int h = hist[t];
        lcur[t] = h ? atomicAdd(&gcur[t], h) : 0;
    }
    __syncthreads();
    for (int j = 0; j < KB_ITEMS; ++j) {
        int r = rr[j];
        if (r >= 0) {
            long i = base + j * KB_BLOCK + threadIdx.x;
            int c; float v;
            if (i < NNZ_FEAT) { c = fcols[i]; v = fvals[i]; }
            else              { c = acols[i - NNZ_FEAT]; v = avals[i - NNZ_FEAT]; }
            int p = atomicAdd(&lcur[r >> 9], 1);
            tmp_row[p] = r;
            tmp_cv[p] = make_int2(c, __float_as_int(v));
        }
    }
}

// ---------------- stage C1: per-bucket row counts (LDS only) ----------------

__global__ __launch_bounds__(256) void kC1(const int* __restrict__ boff,
                                           const int* __restrict__ tmp_row,
                                           int* __restrict__ C) {
    __shared__ int rcnt[BROWS];
    int b = blockIdx.x, rbase = b << 9;
    rcnt[threadIdx.x] = 0;
    rcnt[threadIdx.x + 256] = 0;
    __syncthreads();
    int e0 = boff[b], e1 = boff[b + 1];
    for (int i = e0 + threadIdx.x; i < e1; i += 256)
        atomicAdd(&rcnt[tmp_row[i] - rbase], 1);
    __syncthreads();
    C[rbase + threadIdx.x] = rcnt[threadIdx.x];
    C[rbase + threadIdx.x + 256] = rcnt[threadIdx.x + 256];
}

// ---------------- row-offset scan over NROWP ----------------

__global__ void k_scan1(const int* __restrict__ in, int* __restrict__ out,
                        int* __restrict__ bsums) {
    __shared__ int s[1024];
    int tid = threadIdx.x;
    int i = blockIdx.x * 1024 + tid;
    int v = (i < NROWP) ? in[i] : 0;
    s[tid] = v;
    __syncthreads();
    for (int off = 1; off < 1024; off <<= 1) {
        int t = (tid >= off) ? s[tid - off] : 0;
        __syncthreads();
        s[tid] += t;
        __syncthreads();
    }
    if (i < NROWP) out[i] = s[tid] - v;  // exclusive
    if (tid == 1023) bsums[blockIdx.x] = s[1023];
}

__global__ void k_scan2(int* __restrict__ bsums, int nb) {
    __shared__ int s[256];
    int tid = threadIdx.x;
    int v = (tid < nb) ? bsums[tid] : 0;
    s[tid] = v;
    __syncthreads();
    for (int off = 1; off < 256; off <<= 1) {
        int t = (tid >= off) ? s[tid - off] : 0;
        __syncthreads();
        s[tid] += t;
        __syncthreads();
    }
    if (tid < nb) bsums[tid] = s[tid] - v;
}

__global__ void k_scan3(int* __restrict__ S, const int* __restrict__ bsums) {
    int i = blockIdx.x * 1024 + threadIdx.x;
    if (i < NROWP) S[i] += bsums[blockIdx.x];
}

// ---------------- stage C2: place within bucket (LDS row cursors) ----------------

__global__ __launch_bounds__(256) void kC2(const int* __restrict__ boff,
                                           const int* __restrict__ S,
                                           const int* __restrict__ tmp_row,
                                           const int2* __restrict__ tmp_cv,
                                           int2* __restrict__ pairs) {
    __shared__ int rcur[BROWS];
    int b = blockIdx.x, rbase = b << 9;
    rcur[threadIdx.x] = S[rbase + threadIdx.x];
    rcur[threadIdx.x + 256] = S[rbase + threadIdx.x + 256];
    __syncthreads();
    int e0 = boff[b], e1 = boff[b + 1];
    for (int i = e0 + threadIdx.x; i < e1; i += 256) {
        int r = tmp_row[i];
        int p = atomicAdd(&rcur[r - rbase], 1);
        pairs[p] = tmp_cv[i];
    }
}

// ---------------- SpMM kernels (wave per row, float2/lane, 4-deep MLP) ----------------

__global__ __launch_bounds__(256) void spmm_w(const int* __restrict__ S,
                                              const int2* __restrict__ pairs,
                                              const float* __restrict__ W,
                                              const float* __restrict__ bias,
                                              float* __restrict__ out) {
    int row = blockIdx.x * 4 + (threadIdx.x >> 6);
    int lane = threadIdx.x & 63;
    int k0 = __builtin_amdgcn_readfirstlane(S[row]);
    int k1 = __builtin_amdgcn_readfirstlane(S[row + 1]);
    float2 a0 = ((const float2*)bias)[lane];
    float2 a1 = make_float2(0.0f, 0.0f);
    int k = k0;
    for (; k + 4 <= k1; k += 4) {
        int2 p0 = pairs[k + 0];
        int2 p1 = pairs[k + 1];
        int2 p2 = pairs[k + 2];
        int2 p3 = pairs[k + 3];
        float2 w0 = ((const float2*)(W + (size_t)p0.x * OUT_CH))[lane];
        float2 w1 = ((const float2*)(W + (size_t)p1.x * OUT_CH))[lane];
        float2 w2 = ((const float2*)(W + (size_t)p2.x * OUT_CH))[lane];
        float2 w3 = ((const float2*)(W + (size_t)p3.x * OUT_CH))[lane];
        float v0 = __int_as_float(p0.y), v1 = __int_as_float(p1.y);
        float v2 = __int_as_float(p2.y), v3 = __int_as_float(p3.y);
        a0.x = fmaf(v0, w0.x, a0.x); a0.y = fmaf(v0, w0.y, a0.y);
        a1.x = fmaf(v1, w1.x, a1.x); a1.y = fmaf(v1, w1.y, a1.y);
        a0.x = fmaf(v2, w2.x, a0.x); a0.y = fmaf(v2, w2.y, a0.y);
        a1.x = fmaf(v3, w3.x, a1.x); a1.y = fmaf(v3, w3.y, a1.y);
    }
    for (; k < k1; ++k) {
        int2 p = pairs[k];
        float v = __int_as_float(p.y);
        float2 w = ((const float2*)(W + (size_t)p.x * OUT_CH))[lane];
        a0.x = fmaf(v, w.x, a0.x); a0.y = fmaf(v, w.y, a0.y);
    }
    float2 r;
    r.x = fmaxf(a0.x + a1.x, 0.0f);
    r.y = fmaxf(a0.y + a1.y, 0.0f);
    ((float2*)(out + (size_t)row * OUT_CH))[lane] = r;
}

__global__ __launch_bounds__(256) void spmm_adj(const int* __restrict__ S,
                                                const int2* __restrict__ pairs,
                                                const float* __restrict__ hin,
                                                float* __restrict__ hout) {
    int row = blockIdx.x * 4 + (threadIdx.x >> 6);
    int lane = threadIdx.x & 63;
    int k0 = __builtin_amdgcn_readfirstlane(S[N_NODES + row]);
    int k1 = __builtin_amdgcn_readfirstlane(S[N_NODES + row + 1]);
    float2 a0 = make_float2(0.0f, 0.0f);
    float2 a1 = make_float2(0.0f, 0.0f);
    int k = k0;
    for (; k + 4 <= k1; k += 4) {
        int2 p0 = pairs[k + 0];
        int2 p1 = pairs[k + 1];
        int2 p2 = pairs[k + 2];
        int2 p3 = pairs[k + 3];
        float2 h0 = ((const float2*)(hin + (size_t)p0.x * OUT_CH))[lane];
        float2 h1 = ((const float2*)(hin + (size_t)p1.x * OUT_CH))[lane];
        float2 h2 = ((const float2*)(hin + (size_t)p2.x * OUT_CH))[lane];
        float2 h3 = ((const float2*)(hin + (size_t)p3.x * OUT_CH))[lane];
        float v0 = __int_as_float(p0.y), v1 = __int_as_float(p1.y);
        float v2 = __int_as_float(p2.y), v3 = __int_as_float(p3.y);
        a0.x = fmaf(v0, h0.x, a0.x); a0.y = fmaf(v0, h0.y, a0.y);
        a1.x = fmaf(v1, h1.x, a1.x); a1.y = fmaf(v1, h1.y, a1.y);
        a0.x = fmaf(v2, h2.x, a0.x); a0.y = fmaf(v2, h2.y, a0.y);
        a1.x = fmaf(v3, h3.x, a1.x); a1.y = fmaf(v3, h3.y, a1.y);
    }
    for (; k < k1; ++k) {
        int2 p = pairs[k];
        float v = __int_as_float(p.y);
        float2 h = ((const float2*)(hin + (size_t)p.x * OUT_CH))[lane];
        a0.x = fmaf(v, h.x, a0.x); a0.y = fmaf(v, h.y, a0.y);
    }
    float2 acc;
    acc.x = a0.x + a1.x;
    acc.y = a0.y + a1.y;
    ((float2*)(hout + (size_t)row * OUT_CH))[lane] = acc;
}

// ---------------- driver ----------------

extern "C" void kernel_launch(void* const* d_in, const int* in_sizes, int n_in,
                              void* d_out, int out_size, void* d_ws, size_t ws_size,
                              hipStream_t stream) {
    const int*   frows = (const int*)d_in[0];
    const int*   fcols = (const int*)d_in[1];
    const float* fvals = (const float*)d_in[2];
    const int*   arows = (const int*)d_in[3];
    const int*   acols = (const int*)d_in[4];
    const float* avals = (const float*)d_in[5];
    const float* W     = (const float*)d_in[6];
    const float* bias  = (const float*)d_in[7];
    float* out = (float*)d_out;

    char* ws = (char*)d_ws;
    size_t off = 0;
    auto alloc = [&](size_t bytes) {
        size_t o = off;
        off = (off + bytes + 255) & ~(size_t)255;
        return o;
    };
    int*  C     = (int*) (ws + alloc((size_t)NROWP * 4));
    int*  S     = (int*) (ws + alloc((size_t)NROWP * 4));
    int*  bcnt  = (int*) (ws + alloc(400 * 4));
    int*  boff  = (int*) (ws + alloc(400 * 4));
    int*  gcur  = (int*) (ws + alloc(400 * 4));
    int*  bsum  = (int*) (ws + alloc(256 * 4));
    int2* pairs = (int2*)(ws + alloc((size_t)NNZ_TOT * 8));
    char* hraw  = ws + alloc((size_t)N_NODES * OUT_CH * 4);
    float* hbuf = (float*)hraw;
    // tmp buffers alias onto hbuf: dead before spmm_w runs
    int*  tmp_row = (int*)hraw;                                        // 14.4 MB
    int2* tmp_cv  = (int2*)(hraw + (((size_t)NNZ_TOT * 4 + 255) & ~(size_t)255)); // 28.8 MB
    (void)ws_size; (void)off; (void)in_sizes; (void)n_in; (void)out_size;

    const int nscan = (NROWP + 1023) / 1024;  // 196

    hipMemsetAsync(bcnt, 0, 400 * 4, stream);
    kA<<<KB_GRID, KB_BLOCK, 0, stream>>>(frows, arows, bcnt);
    k_scanb<<<1, 512, 0, stream>>>(bcnt, boff, gcur);
    kB<<<KB_GRID, KB_BLOCK, 0, stream>>>(frows, fcols, fvals, arows, acols, avals,
                                         gcur, tmp_row, tmp_cv);
    kC1<<<NBUCK, 256, 0, stream>>>(boff, tmp_row, C);
    k_scan1<<<nscan, 1024, 0, stream>>>(C, S, bsum);
    k_scan2<<<1, 256, 0, stream>>>(bsum, nscan);
    k_scan3<<<nscan, 1024, 0, stream>>>(S, bsum);
    kC2<<<NBUCK, 256, 0, stream>>>(boff, S, tmp_row, tmp_cv, pairs);

    spmm_w<<<N_NODES / 4, 256, 0, stream>>>(S, pairs, W, bias, hbuf);

    spmm_adj<<<N_NODES / 4, 256, 0, stream>>>(S, pairs, hbuf, out);
    spmm_adj<<<N_NODES / 4, 256, 0, stream>>>(S, pairs, out, hbuf);
    spmm_adj<<<N_NODES / 4, 256, 0, stream>>>(S, pairs, hbuf, out);
}

// Round 5
// 401.403 us; speedup vs baseline: 2.6395x; 1.3519x over previous
//
#include <hip/hip_runtime.h>
#include <hip/hip_fp16.h>

#define N_NODES 100000
#define IN_CH 2048
#define OUT_CH 128
#define NNZ_FEAT 2000000
#define NNZ_ADJ 1600000
#define NNZ_TOT (NNZ_FEAT + NNZ_ADJ)
#define NCOMB (2 * N_NODES)            // combined row space: feat rows then adj rows
#define BROWS 512                      // rows per bucket
#define NBUCK 391                      // ceil(200000 / 512)
#define NROWP (NBUCK * BROWS)          // 200192 padded row-count length
#define KB_BLOCK 256
#define KB_ITEMS 16
#define KB_CHUNK (KB_BLOCK * KB_ITEMS) // 4096
#define KB_GRID ((NNZ_TOT + KB_CHUNK - 1) / KB_CHUNK)  // 879

// ---------------- stage A: bucket histogram (LDS-aggregated) ----------------

__global__ __launch_bounds__(KB_BLOCK) void kA(const int* __restrict__ frows,
                                               const int* __restrict__ arows,
                                               int* __restrict__ bcnt) {
    __shared__ int hist[NBUCK];
    for (int t = threadIdx.x; t < NBUCK; t += KB_BLOCK) hist[t] = 0;
    __syncthreads();
    long base = (long)blockIdx.x * KB_CHUNK;
    for (int j = 0; j < KB_ITEMS; ++j) {
        long i = base + j * KB_BLOCK + threadIdx.x;
        if (i < NNZ_TOT) {
            int r = (i < NNZ_FEAT) ? frows[i] : (N_NODES + arows[i - NNZ_FEAT]);
            atomicAdd(&hist[r >> 9], 1);
        }
    }
    __syncthreads();
    for (int t = threadIdx.x; t < NBUCK; t += KB_BLOCK)
        if (hist[t]) atomicAdd(&bcnt[t], hist[t]);
}

// scan 391 bucket counts in one block of 512; emit boff (exclusive) and gcur copy
__global__ void k_scanb(const int* __restrict__ bcnt, int* __restrict__ boff,
                        int* __restrict__ gcur) {
    __shared__ int s[512];
    int t = threadIdx.x;
    int v = (t < NBUCK) ? bcnt[t] : 0;
    s[t] = v;
    __syncthreads();
    for (int off = 1; off < 512; off <<= 1) {
        int x = (t >= off) ? s[t - off] : 0;
        __syncthreads();
        s[t] += x;
        __syncthreads();
    }
    int e = s[t] - v;
    if (t < NBUCK) { boff[t] = e; gcur[t] = e; }
    if (t == NBUCK - 1) boff[NBUCK] = s[t];
}

// ---------------- stage B: scatter into bucket regions ----------------

__global__ __launch_bounds__(KB_BLOCK) void kB(const int* __restrict__ frows,
                                               const int* __restrict__ fcols,
                                               const float* __restrict__ fvals,
                                               const int* __restrict__ arows,
                                               const int* __restrict__ acols,
                                               const float* __restrict__ avals,
                                               int* __restrict__ gcur,
                                               int* __restrict__ tmp_row,
                                               int2* __restrict__ tmp_cv) {
    __shared__ int hist[NBUCK];
    __shared__ int lcur[NBUCK];
    for (int t = threadIdx.x; t < NBUCK; t += KB_BLOCK) hist[t] = 0;
    __syncthreads();
    long base = (long)blockIdx.x * KB_CHUNK;
    int rr[KB_ITEMS];
    for (int j = 0; j < KB_ITEMS; ++j) {
        long i = base + j * KB_BLOCK + threadIdx.x;
        int r = -1;
        if (i < NNZ_TOT) {
            r = (i < NNZ_FEAT) ? frows[i] : (N_NODES + arows[i - NNZ_FEAT]);
            atomicAdd(&hist[r >> 9], 1);
        }
        rr[j] = r;
    }
    __syncthreads();
    for (int t = threadIdx.x; t < NBUCK; t += KB_BLOCK) {
        int h = hist[t];
        lcur[t] = h ? atomicAdd(&gcur[t], h) : 0;
    }
    __syncthreads();
    for (int j = 0; j < KB_ITEMS; ++j) {
        int r = rr[j];
        if (r >= 0) {
            long i = base + j * KB_BLOCK + threadIdx.x;
            int c; float v;
            if (i < NNZ_FEAT) { c = fcols[i]; v = fvals[i]; }
            else              { c = acols[i - NNZ_FEAT]; v = avals[i - NNZ_FEAT]; }
            int p = atomicAdd(&lcur[r >> 9], 1);
            tmp_row[p] = r;
            tmp_cv[p] = make_int2(c, __float_as_int(v));
        }
    }
}

// ---------------- stage C1: per-bucket row counts (LDS only) ----------------

__global__ __launch_bounds__(256) void kC1(const int* __restrict__ boff,
                                           const int* __restrict__ tmp_row,
                                           int* __restrict__ C) {
    __shared__ int rcnt[BROWS];
    int b = blockIdx.x, rbase = b << 9;
    rcnt[threadIdx.x] = 0;
    rcnt[threadIdx.x + 256] = 0;
    __syncthreads();
    int e0 = boff[b], e1 = boff[b + 1];
    for (int i = e0 + threadIdx.x; i < e1; i += 256)
        atomicAdd(&rcnt[tmp_row[i] - rbase], 1);
    __syncthreads();
    C[rbase + threadIdx.x] = rcnt[threadIdx.x];
    C[rbase + threadIdx.x + 256] = rcnt[threadIdx.x + 256];
}

// ---------------- row-offset scan over NROWP ----------------

__global__ void k_scan1(const int* __restrict__ in, int* __restrict__ out,
                        int* __restrict__ bsums) {
    __shared__ int s[1024];
    int tid = threadIdx.x;
    int i = blockIdx.x * 1024 + tid;
    int v = (i < NROWP) ? in[i] : 0;
    s[tid] = v;
    __syncthreads();
    for (int off = 1; off < 1024; off <<= 1) {
        int t = (tid >= off) ? s[tid - off] : 0;
        __syncthreads();
        s[tid] += t;
        __syncthreads();
    }
    if (i < NROWP) out[i] = s[tid] - v;  // exclusive
    if (tid == 1023) bsums[blockIdx.x] = s[1023];
}

__global__ void k_scan2(int* __restrict__ bsums, int nb) {
    __shared__ int s[256];
    int tid = threadIdx.x;
    int v = (tid < nb) ? bsums[tid] : 0;
    s[tid] = v;
    __syncthreads();
    for (int off = 1; off < 256; off <<= 1) {
        int t = (tid >= off) ? s[tid - off] : 0;
        __syncthreads();
        s[tid] += t;
        __syncthreads();
    }
    if (tid < nb) bsums[tid] = s[tid] - v;
}

__global__ void k_scan3(int* __restrict__ S, const int* __restrict__ bsums) {
    int i = blockIdx.x * 1024 + threadIdx.x;
    if (i < NROWP) S[i] += bsums[blockIdx.x];
}

// ---------------- stage C2: place within bucket (LDS row cursors) ----------------

__global__ __launch_bounds__(256) void kC2(const int* __restrict__ boff,
                                           const int* __restrict__ S,
                                           const int* __restrict__ tmp_row,
                                           const int2* __restrict__ tmp_cv,
                                           int2* __restrict__ pairs) {
    __shared__ int rcur[BROWS];
    int b = blockIdx.x, rbase = b << 9;
    rcur[threadIdx.x] = S[rbase + threadIdx.x];
    rcur[threadIdx.x + 256] = S[rbase + threadIdx.x + 256];
    __syncthreads();
    int e0 = boff[b], e1 = boff[b + 1];
    for (int i = e0 + threadIdx.x; i < e1; i += 256) {
        int r = tmp_row[i];
        int p = atomicAdd(&rcur[r - rbase], 1);
        pairs[p] = tmp_cv[i];
    }
}

// ---------------- SpMM kernels ----------------

// h0 = relu(F*W + b), output fp16. One wave per row, float2/lane over W (fp32).
__global__ __launch_bounds__(256) void spmm_w(const int* __restrict__ S,
                                              const int2* __restrict__ pairs,
                                              const float* __restrict__ W,
                                              const float* __restrict__ bias,
                                              __half2* __restrict__ out16) {
    int row = blockIdx.x * 4 + (threadIdx.x >> 6);
    int lane = threadIdx.x & 63;
    int k0 = __builtin_amdgcn_readfirstlane(S[row]);
    int k1 = __builtin_amdgcn_readfirstlane(S[row + 1]);
    float2 a0 = ((const float2*)bias)[lane];
    float2 a1 = make_float2(0.0f, 0.0f);
    int k = k0;
    for (; k + 4 <= k1; k += 4) {
        int2 p0 = pairs[k + 0];
        int2 p1 = pairs[k + 1];
        int2 p2 = pairs[k + 2];
        int2 p3 = pairs[k + 3];
        float2 w0 = ((const float2*)(W + (size_t)p0.x * OUT_CH))[lane];
        float2 w1 = ((const float2*)(W + (size_t)p1.x * OUT_CH))[lane];
        float2 w2 = ((const float2*)(W + (size_t)p2.x * OUT_CH))[lane];
        float2 w3 = ((const float2*)(W + (size_t)p3.x * OUT_CH))[lane];
        float v0 = __int_as_float(p0.y), v1 = __int_as_float(p1.y);
        float v2 = __int_as_float(p2.y), v3 = __int_as_float(p3.y);
        a0.x = fmaf(v0, w0.x, a0.x); a0.y = fmaf(v0, w0.y, a0.y);
        a1.x = fmaf(v1, w1.x, a1.x); a1.y = fmaf(v1, w1.y, a1.y);
        a0.x = fmaf(v2, w2.x, a0.x); a0.y = fmaf(v2, w2.y, a0.y);
        a1.x = fmaf(v3, w3.x, a1.x); a1.y = fmaf(v3, w3.y, a1.y);
    }
    for (; k < k1; ++k) {
        int2 p = pairs[k];
        float v = __int_as_float(p.y);
        float2 w = ((const float2*)(W + (size_t)p.x * OUT_CH))[lane];
        a0.x = fmaf(v, w.x, a0.x); a0.y = fmaf(v, w.y, a0.y);
    }
    float rx = fmaxf(a0.x + a1.x, 0.0f);
    float ry = fmaxf(a0.y + a1.y, 0.0f);
    out16[(size_t)row * (OUT_CH / 2) + lane] = __floats2half2_rn(rx, ry);
}

// h = A*h, fp16 in -> fp16 out. 8-deep MLP unroll.
__global__ __launch_bounds__(256) void spmm_adj_hh(const int* __restrict__ S,
                                                   const int2* __restrict__ pairs,
                                                   const __half2* __restrict__ hin,
                                                   __half2* __restrict__ hout) {
    int row = blockIdx.x * 4 + (threadIdx.x >> 6);
    int lane = threadIdx.x & 63;
    int k0 = __builtin_amdgcn_readfirstlane(S[N_NODES + row]);
    int k1 = __builtin_amdgcn_readfirstlane(S[N_NODES + row + 1]);
    float2 a0 = make_float2(0.0f, 0.0f);
    float2 a1 = make_float2(0.0f, 0.0f);
    int k = k0;
    for (; k + 8 <= k1; k += 8) {
        int2 p[8];
        __half2 h[8];
#pragma unroll
        for (int j = 0; j < 8; ++j) p[j] = pairs[k + j];
#pragma unroll
        for (int j = 0; j < 8; ++j)
            h[j] = hin[(size_t)p[j].x * (OUT_CH / 2) + lane];
#pragma unroll
        for (int j = 0; j < 8; ++j) {
            float v = __int_as_float(p[j].y);
            float2 f = __half22float2(h[j]);
            if (j & 1) { a1.x = fmaf(v, f.x, a1.x); a1.y = fmaf(v, f.y, a1.y); }
            else       { a0.x = fmaf(v, f.x, a0.x); a0.y = fmaf(v, f.y, a0.y); }
        }
    }
    for (; k < k1; ++k) {
        int2 p = pairs[k];
        float v = __int_as_float(p.y);
        float2 f = __half22float2(hin[(size_t)p.x * (OUT_CH / 2) + lane]);
        a0.x = fmaf(v, f.x, a0.x); a0.y = fmaf(v, f.y, a0.y);
    }
    hout[(size_t)row * (OUT_CH / 2) + lane] = __floats2half2_rn(a0.x + a1.x, a0.y + a1.y);
}

// final hop: fp16 in -> fp32 out (d_out)
__global__ __launch_bounds__(256) void spmm_adj_hf(const int* __restrict__ S,
                                                   const int2* __restrict__ pairs,
                                                   const __half2* __restrict__ hin,
                                                   float* __restrict__ out) {
    int row = blockIdx.x * 4 + (threadIdx.x >> 6);
    int lane = threadIdx.x & 63;
    int k0 = __builtin_amdgcn_readfirstlane(S[N_NODES + row]);
    int k1 = __builtin_amdgcn_readfirstlane(S[N_NODES + row + 1]);
    float2 a0 = make_float2(0.0f, 0.0f);
    float2 a1 = make_float2(0.0f, 0.0f);
    int k = k0;
    for (; k + 8 <= k1; k += 8) {
        int2 p[8];
        __half2 h[8];
#pragma unroll
        for (int j = 0; j < 8; ++j) p[j] = pairs[k + j];
#pragma unroll
        for (int j = 0; j < 8; ++j)
            h[j] = hin[(size_t)p[j].x * (OUT_CH / 2) + lane];
#pragma unroll
        for (int j = 0; j < 8; ++j) {
            float v = __int_as_float(p[j].y);
            float2 f = __half22float2(h[j]);
            if (j & 1) { a1.x = fmaf(v, f.x, a1.x); a1.y = fmaf(v, f.y, a1.y); }
            else       { a0.x = fmaf(v, f.x, a0.x); a0.y = fmaf(v, f.y, a0.y); }
        }
    }
    for (; k < k1; ++k) {
        int2 p = pairs[k];
        float v = __int_as_float(p.y);
        float2 f = __half22float2(hin[(size_t)p.x * (OUT_CH / 2) + lane]);
        a0.x = fmaf(v, f.x, a0.x); a0.y = fmaf(v, f.y, a0.y);
    }
    float2 acc;
    acc.x = a0.x + a1.x;
    acc.y = a0.y + a1.y;
    ((float2*)(out + (size_t)row * OUT_CH))[lane] = acc;
}

// ---------------- driver ----------------

extern "C" void kernel_launch(void* const* d_in, const int* in_sizes, int n_in,
                              void* d_out, int out_size, void* d_ws, size_t ws_size,
                              hipStream_t stream) {
    const int*   frows = (const int*)d_in[0];
    const int*   fcols = (const int*)d_in[1];
    const float* fvals = (const float*)d_in[2];
    const int*   arows = (const int*)d_in[3];
    const int*   acols = (const int*)d_in[4];
    const float* avals = (const float*)d_in[5];
    const float* W     = (const float*)d_in[6];
    const float* bias  = (const float*)d_in[7];
    float* out = (float*)d_out;

    char* ws = (char*)d_ws;
    size_t off = 0;
    auto alloc = [&](size_t bytes) {
        size_t o = off;
        off = (off + bytes + 255) & ~(size_t)255;
        return o;
    };
    int*  C     = (int*) (ws + alloc((size_t)NROWP * 4));
    int*  S     = (int*) (ws + alloc((size_t)NROWP * 4));
    int*  bcnt  = (int*) (ws + alloc(400 * 4));
    int*  boff  = (int*) (ws + alloc(400 * 4));
    int*  gcur  = (int*) (ws + alloc(400 * 4));
    int*  bsum  = (int*) (ws + alloc(256 * 4));
    int2* pairs = (int2*)(ws + alloc((size_t)NNZ_TOT * 8));
    char* hraw  = ws + alloc(2 * (size_t)N_NODES * OUT_CH * 2);   // two fp16 h buffers
    __half2* hA = (__half2*)hraw;
    __half2* hB = (__half2*)(hraw + (size_t)N_NODES * OUT_CH * 2);
    // tmp buffers alias onto hA/hB region: dead before spmm_w runs
    int*  tmp_row = (int*)hraw;                                        // 14.4 MB
    int2* tmp_cv  = (int2*)(hraw + (((size_t)NNZ_TOT * 4 + 255) & ~(size_t)255)); // 28.8 MB
    (void)ws_size; (void)off; (void)in_sizes; (void)n_in; (void)out_size;

    const int nscan = (NROWP + 1023) / 1024;  // 196

    hipMemsetAsync(bcnt, 0, 400 * 4, stream);
    kA<<<KB_GRID, KB_BLOCK, 0, stream>>>(frows, arows, bcnt);
    k_scanb<<<1, 512, 0, stream>>>(bcnt, boff, gcur);
    kB<<<KB_GRID, KB_BLOCK, 0, stream>>>(frows, fcols, fvals, arows, acols, avals,
                                         gcur, tmp_row, tmp_cv);
    kC1<<<NBUCK, 256, 0, stream>>>(boff, tmp_row, C);
    k_scan1<<<nscan, 1024, 0, stream>>>(C, S, bsum);
    k_scan2<<<1, 256, 0, stream>>>(bsum, nscan);
    k_scan3<<<nscan, 1024, 0, stream>>>(S, bsum);
    kC2<<<NBUCK, 256, 0, stream>>>(boff, S, tmp_row, tmp_cv, pairs);

    spmm_w<<<N_NODES / 4, 256, 0, stream>>>(S, pairs, W, bias, hA);

    spmm_adj_hh<<<N_NODES / 4, 256, 0, stream>>>(S, pairs, hA, hB);
    spmm_adj_hh<<<N_NODES / 4, 256, 0, stream>>>(S, pairs, hB, hA);
    spmm_adj_hf<<<N_NODES / 4, 256, 0, stream>>>(S, pairs, hA, out);
}

// Round 6
// 398.258 us; speedup vs baseline: 2.6603x; 1.0079x over previous
//
#include <hip/hip_runtime.h>
#include <hip/hip_fp16.h>

#define N_NODES 100000
#define IN_CH 2048
#define OUT_CH 128
#define NNZ_FEAT 2000000
#define NNZ_ADJ 1600000
#define NNZ_TOT (NNZ_FEAT + NNZ_ADJ)
#define BROWS 512                      // rows per bucket
#define NBUCK 391                      // ceil(200000 / 512)
#define NROWP (NBUCK * BROWS)          // 200192 padded row-count length
#define KB_BLOCK 256
#define KB_ITEMS 16
#define KB_CHUNK (KB_BLOCK * KB_ITEMS) // 4096
#define KB_GRID ((NNZ_TOT + KB_CHUNK - 1) / KB_CHUNK)  // 879

// pack: (row_in_bucket << 17) | col     (col < 131072, rib < 512)
#define PK_COL_BITS 17
#define PK_COL_MASK ((1 << PK_COL_BITS) - 1)

// ---------------- stage A: bucket histogram (LDS-aggregated) ----------------

__global__ __launch_bounds__(KB_BLOCK) void kA(const int* __restrict__ frows,
                                               const int* __restrict__ arows,
                                               int* __restrict__ bcnt) {
    __shared__ int hist[NBUCK];
    for (int t = threadIdx.x; t < NBUCK; t += KB_BLOCK) hist[t] = 0;
    __syncthreads();
    long base = (long)blockIdx.x * KB_CHUNK;
    for (int j = 0; j < KB_ITEMS; ++j) {
        long i = base + j * KB_BLOCK + threadIdx.x;
        if (i < NNZ_TOT) {
            int r = (i < NNZ_FEAT) ? frows[i] : (N_NODES + arows[i - NNZ_FEAT]);
            atomicAdd(&hist[r >> 9], 1);
        }
    }
    __syncthreads();
    for (int t = threadIdx.x; t < NBUCK; t += KB_BLOCK)
        if (hist[t]) atomicAdd(&bcnt[t], hist[t]);
}

// scan 391 bucket counts in one block of 512; emit boff (exclusive) and gcur copy
__global__ void k_scanb(const int* __restrict__ bcnt, int* __restrict__ boff,
                        int* __restrict__ gcur) {
    __shared__ int s[512];
    int t = threadIdx.x;
    int v = (t < NBUCK) ? bcnt[t] : 0;
    s[t] = v;
    __syncthreads();
    for (int off = 1; off < 512; off <<= 1) {
        int x = (t >= off) ? s[t - off] : 0;
        __syncthreads();
        s[t] += x;
        __syncthreads();
    }
    int e = s[t] - v;
    if (t < NBUCK) { boff[t] = e; gcur[t] = e; }
    if (t == NBUCK - 1) boff[NBUCK] = s[t];
}

// ---------------- stage B: LDS bucket-sort then coalesced scatter ----------------

__global__ __launch_bounds__(KB_BLOCK) void kB(const int* __restrict__ frows,
                                               const int* __restrict__ fcols,
                                               const float* __restrict__ fvals,
                                               const int* __restrict__ arows,
                                               const int* __restrict__ acols,
                                               const float* __restrict__ avals,
                                               int* __restrict__ gcur,
                                               int* __restrict__ tmp_pk,
                                               float* __restrict__ tmp_vl) {
    __shared__ int hist[NBUCK];
    __shared__ int lcnt[NBUCK];
    __shared__ int gb[NBUCK];
    __shared__ int bstart[NBUCK];
    __shared__ int sc[512];
    __shared__ int s_pk[KB_CHUNK];
    __shared__ float s_vl[KB_CHUNK];

    int tid = threadIdx.x;
    for (int t = tid; t < NBUCK; t += KB_BLOCK) { hist[t] = 0; lcnt[t] = 0; }
    __syncthreads();

    long base = (long)blockIdx.x * KB_CHUNK;
    int rr[KB_ITEMS];
    for (int j = 0; j < KB_ITEMS; ++j) {
        long i = base + j * KB_BLOCK + tid;
        int r = -1;
        if (i < NNZ_TOT) {
            r = (i < NNZ_FEAT) ? frows[i] : (N_NODES + arows[i - NNZ_FEAT]);
            atomicAdd(&hist[r >> 9], 1);
        }
        rr[j] = r;
    }
    __syncthreads();

    // inclusive scan of hist (padded to 512) with 256 threads handling 2 each
    sc[tid] = (tid < NBUCK) ? hist[tid] : 0;
    sc[tid + 256] = (tid + 256 < NBUCK) ? hist[tid + 256] : 0;
    __syncthreads();
    for (int o = 1; o < 512; o <<= 1) {
        int a0 = (tid >= o) ? sc[tid - o] : 0;
        int a1 = ((tid + 256) >= o) ? sc[tid + 256 - o] : 0;
        __syncthreads();
        sc[tid] += a0;
        sc[tid + 256] += a1;
        __syncthreads();
    }
    for (int t = tid; t < NBUCK; t += KB_BLOCK) {
        int h = hist[t];
        bstart[t] = sc[t] - h;                       // exclusive LDS start
        gb[t] = h ? atomicAdd(&gcur[t], h) : 0;      // reserve global run
    }
    __syncthreads();

    // place items into LDS at bucket-sorted slots
    for (int j = 0; j < KB_ITEMS; ++j) {
        int r = rr[j];
        if (r >= 0) {
            long i = base + j * KB_BLOCK + tid;
            int c; float v;
            if (i < NNZ_FEAT) { c = fcols[i]; v = fvals[i]; }
            else              { c = acols[i - NNZ_FEAT]; v = avals[i - NNZ_FEAT]; }
            int b = r >> 9;
            int slot = bstart[b] + atomicAdd(&lcnt[b], 1);
            s_pk[slot] = ((r & 511) << PK_COL_BITS) | c;
            s_vl[slot] = v;
        }
    }
    __syncthreads();

    // coalesced flush: each wave walks buckets; run in LDS maps to contiguous global run
    int wv = tid >> 6, ln = tid & 63;
    for (int b = wv; b < NBUCK; b += (KB_BLOCK / 64)) {
        int s0 = bstart[b], n = hist[b], g = gb[b];
        for (int o = ln; o < n; o += 64) {
            tmp_pk[g + o] = s_pk[s0 + o];
            tmp_vl[g + o] = s_vl[s0 + o];
        }
    }
}

// ---------------- stage C1: per-bucket row counts (LDS only) ----------------

__global__ __launch_bounds__(256) void kC1(const int* __restrict__ boff,
                                           const int* __restrict__ tmp_pk,
                                           int* __restrict__ C) {
    __shared__ int rcnt[BROWS];
    int b = blockIdx.x, rbase = b << 9;
    rcnt[threadIdx.x] = 0;
    rcnt[threadIdx.x + 256] = 0;
    __syncthreads();
    int e0 = boff[b], e1 = boff[b + 1];
    for (int i = e0 + threadIdx.x; i < e1; i += 256)
        atomicAdd(&rcnt[tmp_pk[i] >> PK_COL_BITS], 1);
    __syncthreads();
    C[rbase + threadIdx.x] = rcnt[threadIdx.x];
    C[rbase + threadIdx.x + 256] = rcnt[threadIdx.x + 256];
}

// ---------------- row-offset scan over NROWP ----------------

__global__ void k_scan1(const int* __restrict__ in, int* __restrict__ out,
                        int* __restrict__ bsums) {
    __shared__ int s[1024];
    int tid = threadIdx.x;
    int i = blockIdx.x * 1024 + tid;
    int v = (i < NROWP) ? in[i] : 0;
    s[tid] = v;
    __syncthreads();
    for (int off = 1; off < 1024; off <<= 1) {
        int t = (tid >= off) ? s[tid - off] : 0;
        __syncthreads();
        s[tid] += t;
        __syncthreads();
    }
    if (i < NROWP) out[i] = s[tid] - v;  // exclusive
    if (tid == 1023) bsums[blockIdx.x] = s[1023];
}

__global__ void k_scan2(int* __restrict__ bsums, int nb) {
    __shared__ int s[256];
    int tid = threadIdx.x;
    int v = (tid < nb) ? bsums[tid] : 0;
    s[tid] = v;
    __syncthreads();
    for (int off = 1; off < 256; off <<= 1) {
        int t = (tid >= off) ? s[tid - off] : 0;
        __syncthreads();
        s[tid] += t;
        __syncthreads();
    }
    if (tid < nb) bsums[tid] = s[tid] - v;
}

__global__ void k_scan3(int* __restrict__ S, const int* __restrict__ bsums) {
    int i = blockIdx.x * 1024 + threadIdx.x;
    if (i < NROWP) S[i] += bsums[blockIdx.x];
}

// ---------------- stage C2: place within bucket (LDS row cursors) ----------------

__global__ __launch_bounds__(256) void kC2(const int* __restrict__ boff,
                                           const int* __restrict__ S,
                                           const int* __restrict__ tmp_pk,
                                           const float* __restrict__ tmp_vl,
                                           int2* __restrict__ pairs) {
    __shared__ int rcur[BROWS];
    int b = blockIdx.x, rbase = b << 9;
    rcur[threadIdx.x] = S[rbase + threadIdx.x];
    rcur[threadIdx.x + 256] = S[rbase + threadIdx.x + 256];
    __syncthreads();
    int e0 = boff[b], e1 = boff[b + 1];
    for (int i = e0 + threadIdx.x; i < e1; i += 256) {
        int pk = tmp_pk[i];
        float v = tmp_vl[i];
        int p = atomicAdd(&rcur[pk >> PK_COL_BITS], 1);
        pairs[p] = make_int2(pk & PK_COL_MASK, __float_as_int(v));
    }
}

// ---------------- SpMM kernels (wave per row, masked unroll-8) ----------------

// h0 = relu(F*W + b), output fp16. W fp32, float2/lane.
__global__ __launch_bounds__(256) void spmm_w(const int* __restrict__ S,
                                              const int2* __restrict__ pairs,
                                              const float* __restrict__ W,
                                              const float* __restrict__ bias,
                                              __half2* __restrict__ out16) {
    int row = blockIdx.x * 4 + (threadIdx.x >> 6);
    int lane = threadIdx.x & 63;
    int k0 = __builtin_amdgcn_readfirstlane(S[row]);
    int k1 = __builtin_amdgcn_readfirstlane(S[row + 1]);
    float2 a0 = ((const float2*)bias)[lane];
    float2 a1 = make_float2(0.0f, 0.0f);
    int len = k1 - k0;
    for (int kk = 0; kk < len; kk += 8) {
        int2 p[8];
        float2 w[8];
#pragma unroll
        for (int j = 0; j < 8; ++j) {
            int idx = k0 + kk + j;
            bool ok = idx < k1;
            int2 pp = pairs[ok ? idx : k0];
            p[j].x = pp.x;
            p[j].y = ok ? pp.y : 0;                 // v = 0 masks lane
        }
#pragma unroll
        for (int j = 0; j < 8; ++j)
            w[j] = ((const float2*)(W + (size_t)p[j].x * OUT_CH))[lane];
#pragma unroll
        for (int j = 0; j < 8; ++j) {
            float v = __int_as_float(p[j].y);
            if (j & 1) { a1.x = fmaf(v, w[j].x, a1.x); a1.y = fmaf(v, w[j].y, a1.y); }
            else       { a0.x = fmaf(v, w[j].x, a0.x); a0.y = fmaf(v, w[j].y, a0.y); }
        }
    }
    float rx = fmaxf(a0.x + a1.x, 0.0f);
    float ry = fmaxf(a0.y + a1.y, 0.0f);
    out16[(size_t)row * (OUT_CH / 2) + lane] = __floats2half2_rn(rx, ry);
}

// h = A*h, fp16 in -> fp16 out
__global__ __launch_bounds__(256) void spmm_adj_hh(const int* __restrict__ S,
                                                   const int2* __restrict__ pairs,
                                                   const __half2* __restrict__ hin,
                                                   __half2* __restrict__ hout) {
    int row = blockIdx.x * 4 + (threadIdx.x >> 6);
    int lane = threadIdx.x & 63;
    int k0 = __builtin_amdgcn_readfirstlane(S[N_NODES + row]);
    int k1 = __builtin_amdgcn_readfirstlane(S[N_NODES + row + 1]);
    float2 a0 = make_float2(0.0f, 0.0f);
    float2 a1 = make_float2(0.0f, 0.0f);
    int len = k1 - k0;
    for (int kk = 0; kk < len; kk += 8) {
        int2 p[8];
        __half2 h[8];
#pragma unroll
        for (int j = 0; j < 8; ++j) {
            int idx = k0 + kk + j;
            bool ok = idx < k1;
            int2 pp = pairs[ok ? idx : k0];
            p[j].x = pp.x;
            p[j].y = ok ? pp.y : 0;
        }
#pragma unroll
        for (int j = 0; j < 8; ++j)
            h[j] = hin[(size_t)p[j].x * (OUT_CH / 2) + lane];
#pragma unroll
        for (int j = 0; j < 8; ++j) {
            float v = __int_as_float(p[j].y);
            float2 f = __half22float2(h[j]);
            if (j & 1) { a1.x = fmaf(v, f.x, a1.x); a1.y = fmaf(v, f.y, a1.y); }
            else       { a0.x = fmaf(v, f.x, a0.x); a0.y = fmaf(v, f.y, a0.y); }
        }
    }
    hout[(size_t)row * (OUT_CH / 2) + lane] = __floats2half2_rn(a0.x + a1.x, a0.y + a1.y);
}

// final hop: fp16 in -> fp32 out (d_out)
__global__ __launch_bounds__(256) void spmm_adj_hf(const int* __restrict__ S,
                                                   const int2* __restrict__ pairs,
                                                   const __half2* __restrict__ hin,
                                                   float* __restrict__ out) {
    int row = blockIdx.x * 4 + (threadIdx.x >> 6);
    int lane = threadIdx.x & 63;
    int k0 = __builtin_amdgcn_readfirstlane(S[N_NODES + row]);
    int k1 = __builtin_amdgcn_readfirstlane(S[N_NODES + row + 1]);
    float2 a0 = make_float2(0.0f, 0.0f);
    float2 a1 = make_float2(0.0f, 0.0f);
    int len = k1 - k0;
    for (int kk = 0; kk < len; kk += 8) {
        int2 p[8];
        __half2 h[8];
#pragma unroll
        for (int j = 0; j < 8; ++j) {
            int idx = k0 + kk + j;
            bool ok = idx < k1;
            int2 pp = pairs[ok ? idx : k0];
            p[j].x = pp.x;
            p[j].y = ok ? pp.y : 0;
        }
#pragma unroll
        for (int j = 0; j < 8; ++j)
            h[j] = hin[(size_t)p[j].x * (OUT_CH / 2) + lane];
#pragma unroll
        for (int j = 0; j < 8; ++j) {
            float v = __int_as_float(p[j].y);
            float2 f = __half22float2(h[j]);
            if (j & 1) { a1.x = fmaf(v, f.x, a1.x); a1.y = fmaf(v, f.y, a1.y); }
            else       { a0.x = fmaf(v, f.x, a0.x); a0.y = fmaf(v, f.y, a0.y); }
        }
    }
    float2 acc;
    acc.x = a0.x + a1.x;
    acc.y = a0.y + a1.y;
    ((float2*)(out + (size_t)row * OUT_CH))[lane] = acc;
}

// ---------------- driver ----------------

extern "C" void kernel_launch(void* const* d_in, const int* in_sizes, int n_in,
                              void* d_out, int out_size, void* d_ws, size_t ws_size,
                              hipStream_t stream) {
    const int*   frows = (const int*)d_in[0];
    const int*   fcols = (const int*)d_in[1];
    const float* fvals = (const float*)d_in[2];
    const int*   arows = (const int*)d_in[3];
    const int*   acols = (const int*)d_in[4];
    const float* avals = (const float*)d_in[5];
    const float* W     = (const float*)d_in[6];
    const float* bias  = (const float*)d_in[7];
    float* out = (float*)d_out;

    char* ws = (char*)d_ws;
    size_t off = 0;
    auto alloc = [&](size_t bytes) {
        size_t o = off;
        off = (off + bytes + 255) & ~(size_t)255;
        return o;
    };
    int*  C     = (int*) (ws + alloc((size_t)NROWP * 4));
    int*  S     = (int*) (ws + alloc((size_t)NROWP * 4));
    int*  bcnt  = (int*) (ws + alloc(400 * 4));
    int*  boff  = (int*) (ws + alloc(400 * 4));
    int*  gcur  = (int*) (ws + alloc(400 * 4));
    int*  bsum  = (int*) (ws + alloc(256 * 4));
    int2* pairs = (int2*)(ws + alloc((size_t)NNZ_TOT * 8));
    char* hraw  = ws + alloc(2 * (size_t)N_NODES * OUT_CH * 2);   // two fp16 h buffers
    __half2* hA = (__half2*)hraw;
    __half2* hB = (__half2*)(hraw + (size_t)N_NODES * OUT_CH * 2);
    // tmp buffers alias onto hA/hB region: dead before spmm_w runs
    int*   tmp_pk = (int*)hraw;                                         // 14.4 MB
    float* tmp_vl = (float*)(hraw + (((size_t)NNZ_TOT * 4 + 255) & ~(size_t)255)); // 14.4 MB
    (void)ws_size; (void)off; (void)in_sizes; (void)n_in; (void)out_size;

    const int nscan = (NROWP + 1023) / 1024;  // 196

    hipMemsetAsync(bcnt, 0, 400 * 4, stream);
    kA<<<KB_GRID, KB_BLOCK, 0, stream>>>(frows, arows, bcnt);
    k_scanb<<<1, 512, 0, stream>>>(bcnt, boff, gcur);
    kB<<<KB_GRID, KB_BLOCK, 0, stream>>>(frows, fcols, fvals, arows, acols, avals,
                                         gcur, tmp_pk, tmp_vl);
    kC1<<<NBUCK, 256, 0, stream>>>(boff, tmp_pk, C);
    k_scan1<<<nscan, 1024, 0, stream>>>(C, S, bsum);
    k_scan2<<<1, 256, 0, stream>>>(bsum, nscan);
    k_scan3<<<nscan, 1024, 0, stream>>>(S, bsum);
    kC2<<<NBUCK, 256, 0, stream>>>(boff, S, tmp_pk, tmp_vl, pairs);

    spmm_w<<<N_NODES / 4, 256, 0, stream>>>(S, pairs, W, bias, hA);

    spmm_adj_hh<<<N_NODES / 4, 256, 0, stream>>>(S, pairs, hA, hB);
    spmm_adj_hh<<<N_NODES / 4, 256, 0, stream>>>(S, pairs, hB, hA);
    spmm_adj_hf<<<N_NODES / 4, 256, 0, stream>>>(S, pairs, hA, out);
}

// Round 7
// 356.318 us; speedup vs baseline: 2.9734x; 1.1177x over previous
//
#include <hip/hip_runtime.h>
#include <hip/hip_fp16.h>

#define N_NODES 100000
#define IN_CH 2048
#define OUT_CH 128
#define NNZ_FEAT 2000000
#define NNZ_ADJ 1600000
#define NNZ_TOT (NNZ_FEAT + NNZ_ADJ)
#define BROWS 512                      // rows per bucket
#define NBUCK 391                      // ceil(200000 / 512)
#define NROWP (NBUCK * BROWS)          // 200192 padded row-count length
#define KB_BLOCK 256
#define KB_ITEMS 16
#define KB_CHUNK (KB_BLOCK * KB_ITEMS) // 4096
#define KB_GRID ((NNZ_TOT + KB_CHUNK - 1) / KB_CHUNK)  // 879

// pack: (row_in_bucket << 17) | col     (col < 131072, rib < 512)
#define PK_COL_BITS 17
#define PK_COL_MASK ((1 << PK_COL_BITS) - 1)

// ---------------- stage A: bucket histogram (LDS-aggregated) ----------------

__global__ __launch_bounds__(KB_BLOCK) void kA(const int* __restrict__ frows,
                                               const int* __restrict__ arows,
                                               int* __restrict__ bcnt) {
    __shared__ int hist[NBUCK];
    for (int t = threadIdx.x; t < NBUCK; t += KB_BLOCK) hist[t] = 0;
    __syncthreads();
    long base = (long)blockIdx.x * KB_CHUNK;
    for (int j = 0; j < KB_ITEMS; ++j) {
        long i = base + j * KB_BLOCK + threadIdx.x;
        if (i < NNZ_TOT) {
            int r = (i < NNZ_FEAT) ? frows[i] : (N_NODES + arows[i - NNZ_FEAT]);
            atomicAdd(&hist[r >> 9], 1);
        }
    }
    __syncthreads();
    for (int t = threadIdx.x; t < NBUCK; t += KB_BLOCK)
        if (hist[t]) atomicAdd(&bcnt[t], hist[t]);
}

// scan 391 bucket counts in one block of 512; emit boff (exclusive) and gcur copy
__global__ void k_scanb(const int* __restrict__ bcnt, int* __restrict__ boff,
                        int* __restrict__ gcur) {
    __shared__ int s[512];
    int t = threadIdx.x;
    int v = (t < NBUCK) ? bcnt[t] : 0;
    s[t] = v;
    __syncthreads();
    for (int off = 1; off < 512; off <<= 1) {
        int x = (t >= off) ? s[t - off] : 0;
        __syncthreads();
        s[t] += x;
        __syncthreads();
    }
    int e = s[t] - v;
    if (t < NBUCK) { boff[t] = e; gcur[t] = e; }
    if (t == NBUCK - 1) boff[NBUCK] = s[t];
}

// ---------------- stage B: LDS bucket-sort then coalesced scatter ----------------

__global__ __launch_bounds__(KB_BLOCK) void kB(const int* __restrict__ frows,
                                               const int* __restrict__ fcols,
                                               const float* __restrict__ fvals,
                                               const int* __restrict__ arows,
                                               const int* __restrict__ acols,
                                               const float* __restrict__ avals,
                                               int* __restrict__ gcur,
                                               int* __restrict__ tmp_pk,
                                               float* __restrict__ tmp_vl) {
    __shared__ int hist[NBUCK];
    __shared__ int lcnt[NBUCK];
    __shared__ int gb[NBUCK];
    __shared__ int bstart[NBUCK];
    __shared__ int sc[512];
    __shared__ int s_pk[KB_CHUNK];
    __shared__ float s_vl[KB_CHUNK];

    int tid = threadIdx.x;
    for (int t = tid; t < NBUCK; t += KB_BLOCK) { hist[t] = 0; lcnt[t] = 0; }
    __syncthreads();

    long base = (long)blockIdx.x * KB_CHUNK;
    int rr[KB_ITEMS];
    for (int j = 0; j < KB_ITEMS; ++j) {
        long i = base + j * KB_BLOCK + tid;
        int r = -1;
        if (i < NNZ_TOT) {
            r = (i < NNZ_FEAT) ? frows[i] : (N_NODES + arows[i - NNZ_FEAT]);
            atomicAdd(&hist[r >> 9], 1);
        }
        rr[j] = r;
    }
    __syncthreads();

    // inclusive scan of hist (padded to 512) with 256 threads handling 2 each
    sc[tid] = (tid < NBUCK) ? hist[tid] : 0;
    sc[tid + 256] = (tid + 256 < NBUCK) ? hist[tid + 256] : 0;
    __syncthreads();
    for (int o = 1; o < 512; o <<= 1) {
        int a0 = (tid >= o) ? sc[tid - o] : 0;
        int a1 = ((tid + 256) >= o) ? sc[tid + 256 - o] : 0;
        __syncthreads();
        sc[tid] += a0;
        sc[tid + 256] += a1;
        __syncthreads();
    }
    for (int t = tid; t < NBUCK; t += KB_BLOCK) {
        int h = hist[t];
        bstart[t] = sc[t] - h;                       // exclusive LDS start
        gb[t] = h ? atomicAdd(&gcur[t], h) : 0;      // reserve global run
    }
    __syncthreads();

    // place items into LDS at bucket-sorted slots
    for (int j = 0; j < KB_ITEMS; ++j) {
        int r = rr[j];
        if (r >= 0) {
            long i = base + j * KB_BLOCK + tid;
            int c; float v;
            if (i < NNZ_FEAT) { c = fcols[i]; v = fvals[i]; }
            else              { c = acols[i - NNZ_FEAT]; v = avals[i - NNZ_FEAT]; }
            int b = r >> 9;
            int slot = bstart[b] + atomicAdd(&lcnt[b], 1);
            s_pk[slot] = ((r & 511) << PK_COL_BITS) | c;
            s_vl[slot] = v;
        }
    }
    __syncthreads();

    // coalesced flush: each wave walks buckets; run in LDS maps to contiguous global run
    int wv = tid >> 6, ln = tid & 63;
    for (int b = wv; b < NBUCK; b += (KB_BLOCK / 64)) {
        int s0 = bstart[b], n = hist[b], g = gb[b];
        for (int o = ln; o < n; o += 64) {
            tmp_pk[g + o] = s_pk[s0 + o];
            tmp_vl[g + o] = s_vl[s0 + o];
        }
    }
}

// ---------------- stage C1: per-bucket row counts (LDS only) ----------------

__global__ __launch_bounds__(256) void kC1(const int* __restrict__ boff,
                                           const int* __restrict__ tmp_pk,
                                           int* __restrict__ C) {
    __shared__ int rcnt[BROWS];
    int b = blockIdx.x, rbase = b << 9;
    rcnt[threadIdx.x] = 0;
    rcnt[threadIdx.x + 256] = 0;
    __syncthreads();
    int e0 = boff[b], e1 = boff[b + 1];
    for (int i = e0 + threadIdx.x; i < e1; i += 256)
        atomicAdd(&rcnt[tmp_pk[i] >> PK_COL_BITS], 1);
    __syncthreads();
    C[rbase + threadIdx.x] = rcnt[threadIdx.x];
    C[rbase + threadIdx.x + 256] = rcnt[threadIdx.x + 256];
}

// ---------------- row-offset scan over NROWP ----------------

__global__ void k_scan1(const int* __restrict__ in, int* __restrict__ out,
                        int* __restrict__ bsums) {
    __shared__ int s[1024];
    int tid = threadIdx.x;
    int i = blockIdx.x * 1024 + tid;
    int v = (i < NROWP) ? in[i] : 0;
    s[tid] = v;
    __syncthreads();
    for (int off = 1; off < 1024; off <<= 1) {
        int t = (tid >= off) ? s[tid - off] : 0;
        __syncthreads();
        s[tid] += t;
        __syncthreads();
    }
    if (i < NROWP) out[i] = s[tid] - v;  // exclusive
    if (tid == 1023) bsums[blockIdx.x] = s[1023];
}

__global__ void k_scan2(int* __restrict__ bsums, int nb) {
    __shared__ int s[256];
    int tid = threadIdx.x;
    int v = (tid < nb) ? bsums[tid] : 0;
    s[tid] = v;
    __syncthreads();
    for (int off = 1; off < 256; off <<= 1) {
        int t = (tid >= off) ? s[tid - off] : 0;
        __syncthreads();
        s[tid] += t;
        __syncthreads();
    }
    if (tid < nb) bsums[tid] = s[tid] - v;
}

__global__ void k_scan3(int* __restrict__ S, const int* __restrict__ bsums) {
    int i = blockIdx.x * 1024 + threadIdx.x;
    if (i < NROWP) S[i] += bsums[blockIdx.x];
}

// ---------------- stage C2: place within bucket (LDS row cursors) ----------------

__global__ __launch_bounds__(256) void kC2(const int* __restrict__ boff,
                                           const int* __restrict__ S,
                                           const int* __restrict__ tmp_pk,
                                           const float* __restrict__ tmp_vl,
                                           int2* __restrict__ pairs) {
    __shared__ int rcur[BROWS];
    int b = blockIdx.x, rbase = b << 9;
    rcur[threadIdx.x] = S[rbase + threadIdx.x];
    rcur[threadIdx.x + 256] = S[rbase + threadIdx.x + 256];
    __syncthreads();
    int e0 = boff[b], e1 = boff[b + 1];
    for (int i = e0 + threadIdx.x; i < e1; i += 256) {
        int pk = tmp_pk[i];
        float v = tmp_vl[i];
        int p = atomicAdd(&rcur[pk >> PK_COL_BITS], 1);
        pairs[p] = make_int2(pk & PK_COL_MASK, __float_as_int(v));
    }
}

// ---------------- W fp32 -> fp16 ----------------

__global__ __launch_bounds__(256) void k_wconv(const float* __restrict__ W,
                                               __half2* __restrict__ Wh) {
    int i = blockIdx.x * 256 + threadIdx.x;
    if (i < IN_CH * OUT_CH / 2) {
        float2 f = ((const float2*)W)[i];
        Wh[i] = __floats2half2_rn(f.x, f.y);
    }
}

// ---------------- SpMM kernels ----------------
// wave per row; lane l preloads pairs[k0+l] for a 64-chunk; (col,val) broadcast
// via readlane -> gathers are SGPR-base loads with no inter-load dependency.

#define SPMM_BODY(HSRC, ACC_INIT)                                              \
    int row = blockIdx.x * 4 + (threadIdx.x >> 6);                             \
    int lane = threadIdx.x & 63;                                               \
    int k0 = __builtin_amdgcn_readfirstlane(SROW0);                            \
    int k1 = __builtin_amdgcn_readfirstlane(SROW1);                            \
    float2 a0 = ACC_INIT;                                                      \
    float2 a1 = make_float2(0.0f, 0.0f);                                       \
    for (int base = k0; base < k1; base += 64) {                               \
        int idx = base + lane;                                                 \
        int2 pp = (idx < k1) ? pairs[idx] : make_int2(0, 0);                   \
        int n = k1 - base; if (n > 64) n = 64;                                 \
        int full = n & ~7;                                                     \
        for (int jj = 0; jj < full; jj += 8) {                                 \
            _Pragma("unroll")                                                  \
            for (int j = 0; j < 8; ++j) {                                      \
                int c = __builtin_amdgcn_readlane(pp.x, jj + j);               \
                float v = __int_as_float(__builtin_amdgcn_readlane(pp.y, jj + j)); \
                float2 f = __half22float2(HSRC[(size_t)c * (OUT_CH / 2) + lane]); \
                if (j & 1) { a1.x = fmaf(v, f.x, a1.x); a1.y = fmaf(v, f.y, a1.y); } \
                else       { a0.x = fmaf(v, f.x, a0.x); a0.y = fmaf(v, f.y, a0.y); } \
            }                                                                  \
        }                                                                      \
        if (full < n) {                                                        \
            _Pragma("unroll")                                                  \
            for (int j = 0; j < 8; ++j) {                                      \
                int c = __builtin_amdgcn_readlane(pp.x, full + j);             \
                float v = __int_as_float(__builtin_amdgcn_readlane(pp.y, full + j)); \
                float2 f = __half22float2(HSRC[(size_t)c * (OUT_CH / 2) + lane]); \
                if (j & 1) { a1.x = fmaf(v, f.x, a1.x); a1.y = fmaf(v, f.y, a1.y); } \
                else       { a0.x = fmaf(v, f.x, a0.x); a0.y = fmaf(v, f.y, a0.y); } \
            }                                                                  \
        }                                                                      \
    }

// h0 = relu(F*Wh + b), output fp16
__global__ __launch_bounds__(256) void spmm_w(const int* __restrict__ S,
                                              const int2* __restrict__ pairs,
                                              const __half2* __restrict__ Wh,
                                              const float* __restrict__ bias,
                                              __half2* __restrict__ out16) {
#define SROW0 S[row]
#define SROW1 S[row + 1]
    SPMM_BODY(Wh, ((const float2*)bias)[lane])
#undef SROW0
#undef SROW1
    float rx = fmaxf(a0.x + a1.x, 0.0f);
    float ry = fmaxf(a0.y + a1.y, 0.0f);
    out16[(size_t)row * (OUT_CH / 2) + lane] = __floats2half2_rn(rx, ry);
}

// h = A*h, fp16 in -> fp16 out
__global__ __launch_bounds__(256) void spmm_adj_hh(const int* __restrict__ S,
                                                   const int2* __restrict__ pairs,
                                                   const __half2* __restrict__ hin,
                                                   __half2* __restrict__ hout) {
#define SROW0 S[N_NODES + row]
#define SROW1 S[N_NODES + row + 1]
    SPMM_BODY(hin, make_float2(0.0f, 0.0f))
#undef SROW0
#undef SROW1
    hout[(size_t)row * (OUT_CH / 2) + lane] = __floats2half2_rn(a0.x + a1.x, a0.y + a1.y);
}

// final hop: fp16 in -> fp32 out (d_out)
__global__ __launch_bounds__(256) void spmm_adj_hf(const int* __restrict__ S,
                                                   const int2* __restrict__ pairs,
                                                   const __half2* __restrict__ hin,
                                                   float* __restrict__ out) {
#define SROW0 S[N_NODES + row]
#define SROW1 S[N_NODES + row + 1]
    SPMM_BODY(hin, make_float2(0.0f, 0.0f))
#undef SROW0
#undef SROW1
    float2 acc;
    acc.x = a0.x + a1.x;
    acc.y = a0.y + a1.y;
    ((float2*)(out + (size_t)row * OUT_CH))[lane] = acc;
}

// ---------------- driver ----------------

extern "C" void kernel_launch(void* const* d_in, const int* in_sizes, int n_in,
                              void* d_out, int out_size, void* d_ws, size_t ws_size,
                              hipStream_t stream) {
    const int*   frows = (const int*)d_in[0];
    const int*   fcols = (const int*)d_in[1];
    const float* fvals = (const float*)d_in[2];
    const int*   arows = (const int*)d_in[3];
    const int*   acols = (const int*)d_in[4];
    const float* avals = (const float*)d_in[5];
    const float* W     = (const float*)d_in[6];
    const float* bias  = (const float*)d_in[7];
    float* out = (float*)d_out;

    char* ws = (char*)d_ws;
    size_t off = 0;
    auto alloc = [&](size_t bytes) {
        size_t o = off;
        off = (off + bytes + 255) & ~(size_t)255;
        return o;
    };
    int*  C     = (int*) (ws + alloc((size_t)NROWP * 4));
    int*  S     = (int*) (ws + alloc((size_t)NROWP * 4));
    int*  bcnt  = (int*) (ws + alloc(400 * 4));
    int*  boff  = (int*) (ws + alloc(400 * 4));
    int*  gcur  = (int*) (ws + alloc(400 * 4));
    int*  bsum  = (int*) (ws + alloc(256 * 4));
    int2* pairs = (int2*)(ws + alloc((size_t)NNZ_TOT * 8));
    __half2* Wh = (__half2*)(ws + alloc((size_t)IN_CH * OUT_CH * 2));
    char* hraw  = ws + alloc(2 * (size_t)N_NODES * OUT_CH * 2);   // two fp16 h buffers
    __half2* hA = (__half2*)hraw;
    __half2* hB = (__half2*)(hraw + (size_t)N_NODES * OUT_CH * 2);
    // tmp buffers alias onto hA/hB region: dead before spmm_w runs
    int*   tmp_pk = (int*)hraw;                                         // 14.4 MB
    float* tmp_vl = (float*)(hraw + (((size_t)NNZ_TOT * 4 + 255) & ~(size_t)255)); // 14.4 MB
    (void)ws_size; (void)off; (void)in_sizes; (void)n_in; (void)out_size;

    const int nscan = (NROWP + 1023) / 1024;  // 196

    hipMemsetAsync(bcnt, 0, 400 * 4, stream);
    k_wconv<<<(IN_CH * OUT_CH / 2 + 255) / 256, 256, 0, stream>>>(W, Wh);
    kA<<<KB_GRID, KB_BLOCK, 0, stream>>>(frows, arows, bcnt);
    k_scanb<<<1, 512, 0, stream>>>(bcnt, boff, gcur);
    kB<<<KB_GRID, KB_BLOCK, 0, stream>>>(frows, fcols, fvals, arows, acols, avals,
                                         gcur, tmp_pk, tmp_vl);
    kC1<<<NBUCK, 256, 0, stream>>>(boff, tmp_pk, C);
    k_scan1<<<nscan, 1024, 0, stream>>>(C, S, bsum);
    k_scan2<<<1, 256, 0, stream>>>(bsum, nscan);
    k_scan3<<<nscan, 1024, 0, stream>>>(S, bsum);
    kC2<<<NBUCK, 256, 0, stream>>>(boff, S, tmp_pk, tmp_vl, pairs);

    spmm_w<<<N_NODES / 4, 256, 0, stream>>>(S, pairs, Wh, bias, hA);

    spmm_adj_hh<<<N_NODES / 4, 256, 0, stream>>>(S, pairs, hA, hB);
    spmm_adj_hh<<<N_NODES / 4, 256, 0, stream>>>(S, pairs, hB, hA);
    spmm_adj_hf<<<N_NODES / 4, 256, 0, stream>>>(S, pairs, hA, out);
}

// Round 8
// 335.357 us; speedup vs baseline: 3.1593x; 1.0625x over previous
//
#include <hip/hip_runtime.h>
#include <hip/hip_fp16.h>

#define N_NODES 100000
#define IN_CH 2048
#define OUT_CH 128
#define NNZ_FEAT 2000000
#define NNZ_ADJ 1600000
#define NNZ_TOT (NNZ_FEAT + NNZ_ADJ)
#define BROWS 512                      // rows per bucket
#define NBUCK 391                      // ceil(200000 / 512)
#define NROWP (NBUCK * BROWS)          // 200192 padded row-count length
#define KB_BLOCK 256
#define KB_ITEMS 16
#define KB_CHUNK (KB_BLOCK * KB_ITEMS) // 4096
#define KB_GRID ((NNZ_TOT + KB_CHUNK - 1) / KB_CHUNK)  // 879

// pack: (row_in_bucket << 17) | col     (col < 131072, rib < 512)
#define PK_COL_BITS 17
#define PK_COL_MASK ((1 << PK_COL_BITS) - 1)

// ---------------- stage A: bucket histogram (LDS-aggregated) ----------------

__global__ __launch_bounds__(KB_BLOCK) void kA(const int* __restrict__ frows,
                                               const int* __restrict__ arows,
                                               int* __restrict__ bcnt) {
    __shared__ int hist[NBUCK];
    for (int t = threadIdx.x; t < NBUCK; t += KB_BLOCK) hist[t] = 0;
    __syncthreads();
    long base = (long)blockIdx.x * KB_CHUNK;
    for (int j = 0; j < KB_ITEMS; ++j) {
        long i = base + j * KB_BLOCK + threadIdx.x;
        if (i < NNZ_TOT) {
            int r = (i < NNZ_FEAT) ? frows[i] : (N_NODES + arows[i - NNZ_FEAT]);
            atomicAdd(&hist[r >> 9], 1);
        }
    }
    __syncthreads();
    for (int t = threadIdx.x; t < NBUCK; t += KB_BLOCK)
        if (hist[t]) atomicAdd(&bcnt[t], hist[t]);
}

// scan 391 bucket counts in one block of 512; emit boff (exclusive) and gcur copy
__global__ void k_scanb(const int* __restrict__ bcnt, int* __restrict__ boff,
                        int* __restrict__ gcur) {
    __shared__ int s[512];
    int t = threadIdx.x;
    int v = (t < NBUCK) ? bcnt[t] : 0;
    s[t] = v;
    __syncthreads();
    for (int off = 1; off < 512; off <<= 1) {
        int x = (t >= off) ? s[t - off] : 0;
        __syncthreads();
        s[t] += x;
        __syncthreads();
    }
    int e = s[t] - v;
    if (t < NBUCK) { boff[t] = e; gcur[t] = e; }
    if (t == NBUCK - 1) boff[NBUCK] = s[t];
}

// ---------------- stage B: LDS bucket-sort then item-parallel coalesced flush ----

__global__ __launch_bounds__(KB_BLOCK) void kB(const int* __restrict__ frows,
                                               const int* __restrict__ fcols,
                                               const float* __restrict__ fvals,
                                               const int* __restrict__ arows,
                                               const int* __restrict__ acols,
                                               const float* __restrict__ avals,
                                               int* __restrict__ gcur,
                                               int* __restrict__ tmp_pk,
                                               float* __restrict__ tmp_vl) {
    __shared__ int hist[NBUCK];
    __shared__ int lcnt[NBUCK];
    __shared__ int gb[NBUCK];
    __shared__ int bstart[NBUCK];
    __shared__ int sc[512];
    __shared__ int s_pk[KB_CHUNK];
    __shared__ float s_vl[KB_CHUNK];
    __shared__ unsigned short s_bid[KB_CHUNK];

    int tid = threadIdx.x;
    for (int t = tid; t < NBUCK; t += KB_BLOCK) { hist[t] = 0; lcnt[t] = 0; }
    __syncthreads();

    long base = (long)blockIdx.x * KB_CHUNK;
    int rr[KB_ITEMS];
    for (int j = 0; j < KB_ITEMS; ++j) {
        long i = base + j * KB_BLOCK + tid;
        int r = -1;
        if (i < NNZ_TOT) {
            r = (i < NNZ_FEAT) ? frows[i] : (N_NODES + arows[i - NNZ_FEAT]);
            atomicAdd(&hist[r >> 9], 1);
        }
        rr[j] = r;
    }
    __syncthreads();

    // inclusive scan of hist (padded to 512) with 256 threads handling 2 each
    sc[tid] = (tid < NBUCK) ? hist[tid] : 0;
    sc[tid + 256] = (tid + 256 < NBUCK) ? hist[tid + 256] : 0;
    __syncthreads();
    for (int o = 1; o < 512; o <<= 1) {
        int a0 = (tid >= o) ? sc[tid - o] : 0;
        int a1 = ((tid + 256) >= o) ? sc[tid + 256 - o] : 0;
        __syncthreads();
        sc[tid] += a0;
        sc[tid + 256] += a1;
        __syncthreads();
    }
    for (int t = tid; t < NBUCK; t += KB_BLOCK) {
        int h = hist[t];
        bstart[t] = sc[t] - h;                       // exclusive LDS start
        gb[t] = h ? atomicAdd(&gcur[t], h) : 0;      // reserve global run
    }
    __syncthreads();
    int tot = sc[NBUCK - 1];                         // items in this block

    // place items into LDS at bucket-sorted slots (record bucket id per slot)
    for (int j = 0; j < KB_ITEMS; ++j) {
        int r = rr[j];
        if (r >= 0) {
            long i = base + j * KB_BLOCK + tid;
            int c; float v;
            if (i < NNZ_FEAT) { c = fcols[i]; v = fvals[i]; }
            else              { c = acols[i - NNZ_FEAT]; v = avals[i - NNZ_FEAT]; }
            int b = r >> 9;
            int slot = bstart[b] + atomicAdd(&lcnt[b], 1);
            s_pk[slot] = ((r & 511) << PK_COL_BITS) | c;
            s_vl[slot] = v;
            s_bid[slot] = (unsigned short)b;
        }
    }
    __syncthreads();

    // item-parallel flush: consecutive slots -> consecutive global addresses
    for (int s = tid; s < tot; s += KB_BLOCK) {
        int b = s_bid[s];
        int dest = gb[b] + (s - bstart[b]);
        tmp_pk[dest] = s_pk[s];
        tmp_vl[dest] = s_vl[s];
    }
}

// ---------------- stage C1: per-bucket row counts (LDS only) ----------------

__global__ __launch_bounds__(256) void kC1(const int* __restrict__ boff,
                                           const int* __restrict__ tmp_pk,
                                           int* __restrict__ C) {
    __shared__ int rcnt[BROWS];
    int b = blockIdx.x, rbase = b << 9;
    rcnt[threadIdx.x] = 0;
    rcnt[threadIdx.x + 256] = 0;
    __syncthreads();
    int e0 = boff[b], e1 = boff[b + 1];
    for (int i = e0 + threadIdx.x; i < e1; i += 256)
        atomicAdd(&rcnt[tmp_pk[i] >> PK_COL_BITS], 1);
    __syncthreads();
    C[rbase + threadIdx.x] = rcnt[threadIdx.x];
    C[rbase + threadIdx.x + 256] = rcnt[threadIdx.x + 256];
}

// ---------------- row-offset scan over NROWP ----------------

__global__ void k_scan1(const int* __restrict__ in, int* __restrict__ out,
                        int* __restrict__ bsums) {
    __shared__ int s[1024];
    int tid = threadIdx.x;
    int i = blockIdx.x * 1024 + tid;
    int v = (i < NROWP) ? in[i] : 0;
    s[tid] = v;
    __syncthreads();
    for (int off = 1; off < 1024; off <<= 1) {
        int t = (tid >= off) ? s[tid - off] : 0;
        __syncthreads();
        s[tid] += t;
        __syncthreads();
    }
    if (i < NROWP) out[i] = s[tid] - v;  // exclusive
    if (tid == 1023) bsums[blockIdx.x] = s[1023];
}

__global__ void k_scan2(int* __restrict__ bsums, int nb) {
    __shared__ int s[256];
    int tid = threadIdx.x;
    int v = (tid < nb) ? bsums[tid] : 0;
    s[tid] = v;
    __syncthreads();
    for (int off = 1; off < 256; off <<= 1) {
        int t = (tid >= off) ? s[tid - off] : 0;
        __syncthreads();
        s[tid] += t;
        __syncthreads();
    }
    if (tid < nb) bsums[tid] = s[tid] - v;
}

__global__ void k_scan3(int* __restrict__ S, const int* __restrict__ bsums) {
    int i = blockIdx.x * 1024 + threadIdx.x;
    if (i < NROWP) S[i] += bsums[blockIdx.x];
}

// ---------------- stage C2: place within bucket (LDS row cursors) ----------------

__global__ __launch_bounds__(256) void kC2(const int* __restrict__ boff,
                                           const int* __restrict__ S,
                                           const int* __restrict__ tmp_pk,
                                           const float* __restrict__ tmp_vl,
                                           int2* __restrict__ pairs) {
    __shared__ int rcur[BROWS];
    int b = blockIdx.x, rbase = b << 9;
    rcur[threadIdx.x] = S[rbase + threadIdx.x];
    rcur[threadIdx.x + 256] = S[rbase + threadIdx.x + 256];
    __syncthreads();
    int e0 = boff[b], e1 = boff[b + 1];
    for (int i = e0 + threadIdx.x; i < e1; i += 256) {
        int pk = tmp_pk[i];
        float v = tmp_vl[i];
        int p = atomicAdd(&rcur[pk >> PK_COL_BITS], 1);
        pairs[p] = make_int2(pk & PK_COL_MASK, __float_as_int(v));
    }
}

// ---------------- W fp32 -> fp16 ----------------

__global__ __launch_bounds__(256) void k_wconv(const float* __restrict__ W,
                                               __half2* __restrict__ Wh) {
    int i = blockIdx.x * 256 + threadIdx.x;
    if (i < IN_CH * OUT_CH / 2) {
        float2 f = ((const float2*)W)[i];
        Wh[i] = __floats2half2_rn(f.x, f.y);
    }
}

// ---------------- SpMM kernels ----------------
// wave per row; lane l preloads pairs[k0+l] for a 64-chunk; (col,val) broadcast
// via readlane -> gathers are SGPR-base loads with no inter-load dependency.

#define SPMM_BODY(HSRC, ACC_INIT)                                              \
    int row = blockIdx.x * 4 + (threadIdx.x >> 6);                             \
    int lane = threadIdx.x & 63;                                               \
    int k0 = __builtin_amdgcn_readfirstlane(SROW0);                            \
    int k1 = __builtin_amdgcn_readfirstlane(SROW1);                            \
    float2 a0 = ACC_INIT;                                                      \
    float2 a1 = make_float2(0.0f, 0.0f);                                       \
    for (int base = k0; base < k1; base += 64) {                               \
        int idx = base + lane;                                                 \
        int2 pp = (idx < k1) ? pairs[idx] : make_int2(0, 0);                   \
        int n = k1 - base; if (n > 64) n = 64;                                 \
        int full = n & ~7;                                                     \
        for (int jj = 0; jj < full; jj += 8) {                                 \
            _Pragma("unroll")                                                  \
            for (int j = 0; j < 8; ++j) {                                      \
                int c = __builtin_amdgcn_readlane(pp.x, jj + j);               \
                float v = __int_as_float(__builtin_amdgcn_readlane(pp.y, jj + j)); \
                float2 f = __half22float2(HSRC[(size_t)c * (OUT_CH / 2) + lane]); \
                if (j & 1) { a1.x = fmaf(v, f.x, a1.x); a1.y = fmaf(v, f.y, a1.y); } \
                else       { a0.x = fmaf(v, f.x, a0.x); a0.y = fmaf(v, f.y, a0.y); } \
            }                                                                  \
        }                                                                      \
        if (full < n) {                                                        \
            _Pragma("unroll")                                                  \
            for (int j = 0; j < 8; ++j) {                                      \
                int c = __builtin_amdgcn_readlane(pp.x, full + j);             \
                float v = __int_as_float(__builtin_amdgcn_readlane(pp.y, full + j)); \
                float2 f = __half22float2(HSRC[(size_t)c * (OUT_CH / 2) + lane]); \
                if (j & 1) { a1.x = fmaf(v, f.x, a1.x); a1.y = fmaf(v, f.y, a1.y); } \
                else       { a0.x = fmaf(v, f.x, a0.x); a0.y = fmaf(v, f.y, a0.y); } \
            }                                                                  \
        }                                                                      \
    }

// h0 = relu(F*Wh + b), output fp16
__global__ __launch_bounds__(256) void spmm_w(const int* __restrict__ S,
                                              const int2* __restrict__ pairs,
                                              const __half2* __restrict__ Wh,
                                              const float* __restrict__ bias,
                                              __half2* __restrict__ out16) {
#define SROW0 S[row]
#define SROW1 S[row + 1]
    SPMM_BODY(Wh, ((const float2*)bias)[lane])
#undef SROW0
#undef SROW1
    float rx = fmaxf(a0.x + a1.x, 0.0f);
    float ry = fmaxf(a0.y + a1.y, 0.0f);
    out16[(size_t)row * (OUT_CH / 2) + lane] = __floats2half2_rn(rx, ry);
}

// h = A*h, fp16 in -> fp16 out
__global__ __launch_bounds__(256) void spmm_adj_hh(const int* __restrict__ S,
                                                   const int2* __restrict__ pairs,
                                                   const __half2* __restrict__ hin,
                                                   __half2* __restrict__ hout) {
#define SROW0 S[N_NODES + row]
#define SROW1 S[N_NODES + row + 1]
    SPMM_BODY(hin, make_float2(0.0f, 0.0f))
#undef SROW0
#undef SROW1
    hout[(size_t)row * (OUT_CH / 2) + lane] = __floats2half2_rn(a0.x + a1.x, a0.y + a1.y);
}

// final hop: fp16 in -> fp32 out (d_out)
__global__ __launch_bounds__(256) void spmm_adj_hf(const int* __restrict__ S,
                                                   const int2* __restrict__ pairs,
                                                   const __half2* __restrict__ hin,
                                                   float* __restrict__ out) {
#define SROW0 S[N_NODES + row]
#define SROW1 S[N_NODES + row + 1]
    SPMM_BODY(hin, make_float2(0.0f, 0.0f))
#undef SROW0
#undef SROW1
    float2 acc;
    acc.x = a0.x + a1.x;
    acc.y = a0.y + a1.y;
    ((float2*)(out + (size_t)row * OUT_CH))[lane] = acc;
}

// ---------------- driver ----------------

extern "C" void kernel_launch(void* const* d_in, const int* in_sizes, int n_in,
                              void* d_out, int out_size, void* d_ws, size_t ws_size,
                              hipStream_t stream) {
    const int*   frows = (const int*)d_in[0];
    const int*   fcols = (const int*)d_in[1];
    const float* fvals = (const float*)d_in[2];
    const int*   arows = (const int*)d_in[3];
    const int*   acols = (const int*)d_in[4];
    const float* avals = (const float*)d_in[5];
    const float* W     = (const float*)d_in[6];
    const float* bias  = (const float*)d_in[7];
    float* out = (float*)d_out;

    char* ws = (char*)d_ws;
    size_t off = 0;
    auto alloc = [&](size_t bytes) {
        size_t o = off;
        off = (off + bytes + 255) & ~(size_t)255;
        return o;
    };
    int*  C     = (int*) (ws + alloc((size_t)NROWP * 4));
    int*  S     = (int*) (ws + alloc((size_t)NROWP * 4));
    int*  bcnt  = (int*) (ws + alloc(400 * 4));
    int*  boff  = (int*) (ws + alloc(400 * 4));
    int*  gcur  = (int*) (ws + alloc(400 * 4));
    int*  bsum  = (int*) (ws + alloc(256 * 4));
    int2* pairs = (int2*)(ws + alloc((size_t)NNZ_TOT * 8));
    __half2* Wh = (__half2*)(ws + alloc((size_t)IN_CH * OUT_CH * 2));
    char* hraw  = ws + alloc(2 * (size_t)N_NODES * OUT_CH * 2);   // two fp16 h buffers
    __half2* hA = (__half2*)hraw;
    __half2* hB = (__half2*)(hraw + (size_t)N_NODES * OUT_CH * 2);
    // tmp buffers alias onto hA/hB region: dead before spmm_w runs
    int*   tmp_pk = (int*)hraw;                                         // 14.4 MB
    float* tmp_vl = (float*)(hraw + (((size_t)NNZ_TOT * 4 + 255) & ~(size_t)255)); // 14.4 MB
    (void)ws_size; (void)off; (void)in_sizes; (void)n_in; (void)out_size;

    const int nscan = (NROWP + 1023) / 1024;  // 196

    hipMemsetAsync(bcnt, 0, 400 * 4, stream);
    k_wconv<<<(IN_CH * OUT_CH / 2 + 255) / 256, 256, 0, stream>>>(W, Wh);
    kA<<<KB_GRID, KB_BLOCK, 0, stream>>>(frows, arows, bcnt);
    k_scanb<<<1, 512, 0, stream>>>(bcnt, boff, gcur);
    kB<<<KB_GRID, KB_BLOCK, 0, stream>>>(frows, fcols, fvals, arows, acols, avals,
                                         gcur, tmp_pk, tmp_vl);
    kC1<<<NBUCK, 256, 0, stream>>>(boff, tmp_pk, C);
    k_scan1<<<nscan, 1024, 0, stream>>>(C, S, bsum);
    k_scan2<<<1, 256, 0, stream>>>(bsum, nscan);
    k_scan3<<<nscan, 1024, 0, stream>>>(S, bsum);
    kC2<<<NBUCK, 256, 0, stream>>>(boff, S, tmp_pk, tmp_vl, pairs);

    spmm_w<<<N_NODES / 4, 256, 0, stream>>>(S, pairs, Wh, bias, hA);

    spmm_adj_hh<<<N_NODES / 4, 256, 0, stream>>>(S, pairs, hA, hB);
    spmm_adj_hh<<<N_NODES / 4, 256, 0, stream>>>(S, pairs, hB, hA);
    spmm_adj_hf<<<N_NODES / 4, 256, 0, stream>>>(S, pairs, hA, out);
}